// Round 1
// baseline (1153.370 us; speedup 1.0000x reference)
//
#include <hip/hip_runtime.h>
#include <cstdint>
#include <cstddef>

#define BB   2
#define SEQ  4096
#define DD   768
#define HH   12
#define DHH  64
#define DFFN 3072
#define NTOK (BB*SEQ)

using bf16x8 = __attribute__((ext_vector_type(8))) __bf16;
using f32x4  = __attribute__((ext_vector_type(4))) float;

__device__ __forceinline__ unsigned short f2bf(float f) {
    unsigned u = __float_as_uint(f);
    u = u + 0x7FFFu + ((u >> 16) & 1u);
    return (unsigned short)(u >> 16);
}

__device__ __forceinline__ bf16x8 ld_bf8(const unsigned short* p) {
    return *(const bf16x8*)p;   // 16B aligned by construction -> ds_read_b128 / global_load_dwordx4
}

// ---------------- weight prep: fp32 [R][C] -> bf16 transposed [C][R] ----------------
__global__ __launch_bounds__(256) void transpose_f32_to_bf16(
    const float* __restrict__ src, unsigned short* __restrict__ dst, int R, int C)
{
    __shared__ float tile[32][33];
    const int c0 = blockIdx.x * 32, r0 = blockIdx.y * 32;
    const int tx = threadIdx.x, ty = threadIdx.y;   // block (32,8)
#pragma unroll
    for (int i = 0; i < 32; i += 8)
        tile[ty + i][tx] = src[(size_t)(r0 + ty + i) * C + c0 + tx];
    __syncthreads();
#pragma unroll
    for (int i = 0; i < 32; i += 8)
        dst[(size_t)(c0 + ty + i) * R + r0 + tx] = f2bf(tile[tx][ty + i]);
}

__global__ void concat_bias(const float* __restrict__ bq, const float* __restrict__ bk,
                            const float* __restrict__ bv, float* __restrict__ bqkv)
{
    int i = blockIdx.x * 256 + threadIdx.x;
    if (i < 3 * DD)
        bqkv[i] = (i < DD) ? bq[i] : (i < 2 * DD ? bk[i - DD] : bv[i - 2 * DD]);
}

// ---------------- LayerNorm (torch.std semantics: ddof=1, denom = sigma + eps) ------
// out_ln (bf16) = gamma*(v-mu)/(sigma+eps)+beta, v = x (+ add).  Optionally writes v (fp32).
__global__ __launch_bounds__(256) void ln_fused(
    const float* __restrict__ x, const float* __restrict__ add,
    const float* __restrict__ gamma, const float* __restrict__ beta,
    unsigned short* __restrict__ out_ln, float* __restrict__ x1out)
{
    const int row = blockIdx.x, t = threadIdx.x;
    const size_t base = (size_t)row * DD;
    float v[3], s = 0.f, sq = 0.f;
#pragma unroll
    for (int p = 0; p < 3; ++p) {
        int idx = t + p * 256;
        float val = x[base + idx];
        if (add) val += add[base + idx];
        v[p] = val; s += val; sq += val * val;
    }
#pragma unroll
    for (int off = 1; off < 64; off <<= 1) {
        s  += __shfl_xor(s,  off);
        sq += __shfl_xor(sq, off);
    }
    __shared__ float red[8];
    const int wave = t >> 6;
    if ((t & 63) == 0) { red[wave] = s; red[4 + wave] = sq; }
    __syncthreads();
    s  = red[0] + red[1] + red[2] + red[3];
    sq = red[4] + red[5] + red[6] + red[7];
    const float mu   = s * (1.f / 768.f);
    const float var  = fmaxf((sq - 768.f * mu * mu) * (1.f / 767.f), 0.f);
    const float rstd = 1.f / (sqrtf(var) + 1e-6f);
#pragma unroll
    for (int p = 0; p < 3; ++p) {
        int idx = t + p * 256;
        if (x1out) x1out[base + idx] = v[p];
        out_ln[base + idx] = f2bf(gamma[idx] * (v[p] - mu) * rstd + beta[idx]);
    }
}

// ---------------- bf16 GEMM: C[M,N] = A[M,K] * Bt[N,K]^T + bias (+resid) (+relu) ----
// 128x128 tile, BK=32, 4 waves each 64x64 as 4x4 of 16x16x32 MFMA.
__global__ __launch_bounds__(256) void gemm_bf16(
    const unsigned short* __restrict__ A, const unsigned short* __restrict__ Bt,
    const float* __restrict__ bias, const float* __restrict__ resid,
    unsigned short* __restrict__ outB, float* __restrict__ outF,
    int M, int N, int K, int relu)
{
    __shared__ __align__(16) unsigned short As[128][32];
    __shared__ __align__(16) unsigned short Bs[128][32];
    const int tid = threadIdx.x;
    const int lane = tid & 63, wave = tid >> 6;
    const int quad = lane >> 4, l16 = lane & 15;
    const int wm = wave >> 1, wn = wave & 1;
    const int m0 = blockIdx.y * 128, n0 = blockIdx.x * 128;

    const f32x4 fzero = {0.f, 0.f, 0.f, 0.f};
    f32x4 acc[4][4];
#pragma unroll
    for (int i = 0; i < 4; ++i)
#pragma unroll
        for (int j = 0; j < 4; ++j) acc[i][j] = fzero;

    for (int k0 = 0; k0 < K; k0 += 32) {
#pragma unroll
        for (int p = 0; p < 2; ++p) {
            int c = tid + p * 256;
            int r = c >> 2, c8 = (c & 3) * 8;
            *(uint4*)&As[r][c8] = *(const uint4*)&A [(size_t)(m0 + r) * K + k0 + c8];
            *(uint4*)&Bs[r][c8] = *(const uint4*)&Bt[(size_t)(n0 + r) * K + k0 + c8];
        }
        __syncthreads();
        bf16x8 af[4], bfv[4];
#pragma unroll
        for (int i = 0; i < 4; ++i) af[i]  = ld_bf8(&As[wm * 64 + i * 16 + l16][quad * 8]);
#pragma unroll
        for (int j = 0; j < 4; ++j) bfv[j] = ld_bf8(&Bs[wn * 64 + j * 16 + l16][quad * 8]);
#pragma unroll
        for (int i = 0; i < 4; ++i)
#pragma unroll
            for (int j = 0; j < 4; ++j)
                acc[i][j] = __builtin_amdgcn_mfma_f32_16x16x32_bf16(af[i], bfv[j], acc[i][j], 0, 0, 0);
        __syncthreads();
    }
#pragma unroll
    for (int i = 0; i < 4; ++i)
#pragma unroll
        for (int j = 0; j < 4; ++j)
#pragma unroll
            for (int r = 0; r < 4; ++r) {
                const int gm = m0 + wm * 64 + i * 16 + quad * 4 + r;
                const int gn = n0 + wn * 64 + j * 16 + l16;
                float v = acc[i][j][r] + bias[gn];
                if (relu) v = fmaxf(v, 0.f);
                if (resid) v += resid[(size_t)gm * N + gn];
                if (outF) outF[(size_t)gm * N + gn] = v;
                if (outB) outB[(size_t)gm * N + gn] = f2bf(v);
            }
}

// ---------------- flash attention: one block = (b, h, 64 q rows), online softmax ----
// qkv rows: [Q(768) | K(768) | V(768)] bf16; head h occupies cols h*64..h*64+63 of each.
__global__ __launch_bounds__(256) void flash_attn(
    const unsigned short* __restrict__ qkv, const float* __restrict__ mask,
    float* __restrict__ ctx)
{
    __shared__ __align__(16) unsigned short Ks[32][64];   // [k_local][d]
    __shared__ __align__(16) unsigned short Vt[64][32];   // [d][k_local] (transposed)
    __shared__ __align__(16) unsigned short Ps[4][16][32];// per-wave P staging
    const int tid = threadIdx.x;
    const int lane = tid & 63, wave = tid >> 6;
    const int quad = lane >> 4, l16 = lane & 15;
    const int bh = blockIdx.x;
    const int b = bh / HH, h = bh % HH;
    const int q0 = blockIdx.y * 64 + wave * 16;           // this wave's 16 q rows

    // Q fragments (A-layout): Q[m=l16][k=quad*8+j], two frags cover d=0..63
    const size_t qrow = (size_t)(b * SEQ + q0 + l16) * 2304;
    const bf16x8 qf0 = ld_bf8(&qkv[qrow + h * 64 + quad * 8]);
    const bf16x8 qf1 = ld_bf8(&qkv[qrow + h * 64 + 32 + quad * 8]);

    const f32x4 fzero = {0.f, 0.f, 0.f, 0.f};
    float m_run[4], l_run[4];
    f32x4 o[4];
#pragma unroll
    for (int r = 0; r < 4; ++r) { m_run[r] = -1e30f; l_run[r] = 0.f; }
#pragma unroll
    for (int t = 0; t < 4; ++t) o[t] = fzero;

    const int sr = tid >> 3, sc8 = (tid & 7) * 8;         // staging: 32 rows x 64 cols
    const float* mbase = mask + (size_t)b * SEQ * SEQ;

    for (int k0 = 0; k0 < SEQ; k0 += 32) {
        {   // stage K tile + transposed V tile
            const size_t krow = (size_t)(b * SEQ + k0 + sr) * 2304;
            *(uint4*)&Ks[sr][sc8] = *(const uint4*)&qkv[krow + 768 + h * 64 + sc8];
            uint4 vv = *(const uint4*)&qkv[krow + 1536 + h * 64 + sc8];
            const unsigned short* vs = (const unsigned short*)&vv;
#pragma unroll
            for (int j = 0; j < 8; ++j) Vt[sc8 + j][sr] = vs[j];
        }
        __syncthreads();

        // scores: two 16x16 tiles (k cols 0..15, 16..31), K-dim 64 = 2 MFMAs each
        f32x4 st0 = fzero, st1 = fzero;
        {
            bf16x8 kf0 = ld_bf8(&Ks[l16][quad * 8]);
            bf16x8 kf1 = ld_bf8(&Ks[l16][32 + quad * 8]);
            st0 = __builtin_amdgcn_mfma_f32_16x16x32_bf16(qf0, kf0, st0, 0, 0, 0);
            st0 = __builtin_amdgcn_mfma_f32_16x16x32_bf16(qf1, kf1, st0, 0, 0, 0);
            bf16x8 kg0 = ld_bf8(&Ks[16 + l16][quad * 8]);
            bf16x8 kg1 = ld_bf8(&Ks[16 + l16][32 + quad * 8]);
            st1 = __builtin_amdgcn_mfma_f32_16x16x32_bf16(qf0, kg0, st1, 0, 0, 0);
            st1 = __builtin_amdgcn_mfma_f32_16x16x32_bf16(qf1, kg1, st1, 0, 0, 0);
        }
        // scale + multiplicative mask (pre-softmax)
#pragma unroll
        for (int r = 0; r < 4; ++r) {
            const int qq = q0 + quad * 4 + r;
            st0[r] = st0[r] * 0.125f * mbase[(size_t)qq * SEQ + k0 + l16];
            st1[r] = st1[r] * 0.125f * mbase[(size_t)qq * SEQ + k0 + 16 + l16];
        }
        // online softmax (row state per reg r; row-reduce across the quad's 16 lanes)
        float p0[4], p1[4], alpha[4];
#pragma unroll
        for (int r = 0; r < 4; ++r) {
            float mx = fmaxf(st0[r], st1[r]);
#pragma unroll
            for (int off = 1; off < 16; off <<= 1) mx = fmaxf(mx, __shfl_xor(mx, off));
            const float mnew = fmaxf(m_run[r], mx);
            alpha[r] = __expf(m_run[r] - mnew);
            p0[r] = __expf(st0[r] - mnew);
            p1[r] = __expf(st1[r] - mnew);
            float ps = p0[r] + p1[r];
#pragma unroll
            for (int off = 1; off < 16; off <<= 1) ps += __shfl_xor(ps, off);
            l_run[r] = l_run[r] * alpha[r] + ps;
            m_run[r] = mnew;
        }
#pragma unroll
        for (int t = 0; t < 4; ++t)
#pragma unroll
            for (int r = 0; r < 4; ++r) o[t][r] *= alpha[r];
        // P (C-layout) -> LDS, re-read in A-layout
#pragma unroll
        for (int r = 0; r < 4; ++r) {
            Ps[wave][quad * 4 + r][l16]      = f2bf(p0[r]);
            Ps[wave][quad * 4 + r][16 + l16] = f2bf(p1[r]);
        }
        __syncthreads();
        const bf16x8 pf = ld_bf8(&Ps[wave][l16][quad * 8]);
#pragma unroll
        for (int t = 0; t < 4; ++t) {
            bf16x8 vf = ld_bf8(&Vt[t * 16 + l16][quad * 8]);  // B[k][n]=V[k][dh]
            o[t] = __builtin_amdgcn_mfma_f32_16x16x32_bf16(pf, vf, o[t], 0, 0, 0);
        }
        __syncthreads();
    }
#pragma unroll
    for (int t = 0; t < 4; ++t)
#pragma unroll
        for (int r = 0; r < 4; ++r) {
            const int qq = q0 + quad * 4 + r;
            ctx[(size_t)(b * SEQ + qq) * DD + h * 64 + t * 16 + l16] = o[t][r] / l_run[r];
        }
}

// -----------------------------------------------------------------------------------
extern "C" void kernel_launch(void* const* d_in, const int* in_sizes, int n_in,
                              void* d_out, int out_size, void* d_ws, size_t ws_size,
                              hipStream_t stream)
{
    (void)in_sizes; (void)n_in; (void)out_size; (void)ws_size;
    const float* x      = (const float*)d_in[0];
    const float* mask   = (const float*)d_in[1];
    const float* wq     = (const float*)d_in[2];
    const float* bq     = (const float*)d_in[3];
    const float* wk     = (const float*)d_in[4];
    const float* bk     = (const float*)d_in[5];
    const float* wv     = (const float*)d_in[6];
    const float* bv     = (const float*)d_in[7];
    // d_in[8]=wo, d_in[9]=bo: reference never applies out_linear — intentionally unused
    const float* w1     = (const float*)d_in[10];
    const float* b1     = (const float*)d_in[11];
    const float* w2     = (const float*)d_in[12];
    const float* b2     = (const float*)d_in[13];
    const float* gamma1 = (const float*)d_in[14];
    const float* beta1  = (const float*)d_in[15];
    const float* gamma2 = (const float*)d_in[16];
    const float* beta2  = (const float*)d_in[17];
    float* out = (float*)d_out;

    char* ws = (char*)d_ws;
    size_t off = 0;
    auto take = [&](size_t bytes) -> char* {
        char* p = ws + off;
        off = (off + bytes + 255) & ~(size_t)255;
        return p;
    };
    unsigned short* wqkvT = (unsigned short*)take((size_t)2304 * 768 * 2);  // [2304][768]
    unsigned short* w1T   = (unsigned short*)take((size_t)3072 * 768 * 2);  // [3072][768]
    unsigned short* w2T   = (unsigned short*)take((size_t)768 * 3072 * 2);  // [768][3072]
    float*          bqkv  = (float*)take(2304 * 4);
    unsigned short* l12   = (unsigned short*)take((size_t)NTOK * DD * 2);   // l1 then l2
    unsigned short* qkv   = (unsigned short*)take((size_t)NTOK * 2304 * 2);
    float*          x1    = (float*)take((size_t)NTOK * DD * 4);
    char*           hbraw = take((size_t)NTOK * DFFN * 2);                  // hb; first 25MB doubles as ctx
    float*          ctx   = (float*)hbraw;        // dead before hb is written
    unsigned short* hb    = (unsigned short*)hbraw;
    // total ws: ~139 MB

    // weight prep (re-done every call; harness re-poisons ws)
    transpose_f32_to_bf16<<<dim3(24, 24), dim3(32, 8), 0, stream>>>(wq, wqkvT,                 768, 768);
    transpose_f32_to_bf16<<<dim3(24, 24), dim3(32, 8), 0, stream>>>(wk, wqkvT + 768 * 768,     768, 768);
    transpose_f32_to_bf16<<<dim3(24, 24), dim3(32, 8), 0, stream>>>(wv, wqkvT + 2 * 768 * 768, 768, 768);
    transpose_f32_to_bf16<<<dim3(96, 24), dim3(32, 8), 0, stream>>>(w1, w1T,                   768, 3072);
    transpose_f32_to_bf16<<<dim3(24, 96), dim3(32, 8), 0, stream>>>(w2, w2T,                   3072, 768);
    concat_bias<<<9, 256, 0, stream>>>(bq, bk, bv, bqkv);

    // LN1 -> l1 (bf16)
    ln_fused<<<NTOK, 256, 0, stream>>>(x, nullptr, gamma1, beta1, l12, nullptr);
    // fused QKV GEMM: [8192,768] x [768,2304] -> qkv bf16
    gemm_bf16<<<dim3(2304 / 128, NTOK / 128), 256, 0, stream>>>(
        l12, wqkvT, bqkv, nullptr, qkv, nullptr, NTOK, 2304, 768, 0);
    // flash attention -> ctx fp32 [8192,768]
    flash_attn<<<dim3(BB * HH, SEQ / 64), 256, 0, stream>>>(qkv, mask, ctx);
    // x1 = x + ctx (fp32), LN2 -> l2 (bf16)
    ln_fused<<<NTOK, 256, 0, stream>>>(x, ctx, gamma2, beta2, l12, x1);
    // FFN1: relu(l2 @ w1 + b1) -> hb bf16 [8192,3072]
    gemm_bf16<<<dim3(3072 / 128, NTOK / 128), 256, 0, stream>>>(
        l12, w1T, b1, nullptr, hb, nullptr, NTOK, 3072, 768, 1);
    // FFN2: hb @ w2 + b2 + x1 -> out fp32 [8192,768]
    gemm_bf16<<<dim3(768 / 128, NTOK / 128), 256, 0, stream>>>(
        hb, w2T, b2, x1, nullptr, out, NTOK, 768, 3072, 0);
}

// Round 2
// 1034.026 us; speedup vs baseline: 1.1154x; 1.1154x over previous
//
#include <hip/hip_runtime.h>
#include <cstdint>
#include <cstddef>

#define BB   2
#define SEQ  4096
#define DD   768
#define HH   12
#define DHH  64
#define DFFN 3072
#define NTOK (BB*SEQ)

using bf16x8 = __attribute__((ext_vector_type(8))) __bf16;
using f32x4  = __attribute__((ext_vector_type(4))) float;

__device__ __forceinline__ unsigned short f2bf(float f) {
    unsigned u = __float_as_uint(f);
    u = u + 0x7FFFu + ((u >> 16) & 1u);
    return (unsigned short)(u >> 16);
}

__device__ __forceinline__ bf16x8 ld_bf8(const unsigned short* p) {
    return *(const bf16x8*)p;   // 16B aligned by construction
}

// ---------------- weight prep: fp32 [R][C] -> bf16 transposed [C][R], * scale -------
__global__ __launch_bounds__(256) void transpose_f32_to_bf16(
    const float* __restrict__ src, unsigned short* __restrict__ dst, int R, int C, float scale)
{
    __shared__ float tile[32][33];
    const int c0 = blockIdx.x * 32, r0 = blockIdx.y * 32;
    const int tx = threadIdx.x, ty = threadIdx.y;   // block (32,8)
#pragma unroll
    for (int i = 0; i < 32; i += 8)
        tile[ty + i][tx] = src[(size_t)(r0 + ty + i) * C + c0 + tx];
    __syncthreads();
#pragma unroll
    for (int i = 0; i < 32; i += 8)
        dst[(size_t)(c0 + ty + i) * R + r0 + tx] = f2bf(scale * tile[tx][ty + i]);
}

__global__ void concat_bias(const float* __restrict__ bq, const float* __restrict__ bk,
                            const float* __restrict__ bv, float* __restrict__ bqkv)
{
    int i = blockIdx.x * 256 + threadIdx.x;
    if (i < 3 * DD)
        bqkv[i] = (i < DD) ? bq[i] * 0.125f : (i < 2 * DD ? bk[i - DD] : bv[i - 2 * DD]);
}

// ---------------- LayerNorm (torch.std semantics: ddof=1, denom = sigma + eps) ------
__global__ __launch_bounds__(256) void ln_fused(
    const float* __restrict__ x, const float* __restrict__ add,
    const float* __restrict__ gamma, const float* __restrict__ beta,
    unsigned short* __restrict__ out_ln, float* __restrict__ x1out)
{
    const int row = blockIdx.x, t = threadIdx.x;
    const size_t base = (size_t)row * DD;
    float v[3], s = 0.f, sq = 0.f;
#pragma unroll
    for (int p = 0; p < 3; ++p) {
        int idx = t + p * 256;
        float val = x[base + idx];
        if (add) val += add[base + idx];
        v[p] = val; s += val; sq += val * val;
    }
#pragma unroll
    for (int off = 1; off < 64; off <<= 1) {
        s  += __shfl_xor(s,  off);
        sq += __shfl_xor(sq, off);
    }
    __shared__ float red[8];
    const int wave = t >> 6;
    if ((t & 63) == 0) { red[wave] = s; red[4 + wave] = sq; }
    __syncthreads();
    s  = red[0] + red[1] + red[2] + red[3];
    sq = red[4] + red[5] + red[6] + red[7];
    const float mu   = s * (1.f / 768.f);
    const float var  = fmaxf((sq - 768.f * mu * mu) * (1.f / 767.f), 0.f);
    const float rstd = 1.f / (sqrtf(var) + 1e-6f);
#pragma unroll
    for (int p = 0; p < 3; ++p) {
        int idx = t + p * 256;
        if (x1out) x1out[base + idx] = v[p];
        out_ln[base + idx] = f2bf(gamma[idx] * (v[p] - mu) * rstd + beta[idx]);
    }
}

// ---------------- bf16 GEMM: C[M,N] = A[M,K] * Bt[N,K]^T + bias (+resid) (+relu) ----
__global__ __launch_bounds__(256) void gemm_bf16(
    const unsigned short* __restrict__ A, const unsigned short* __restrict__ Bt,
    const float* __restrict__ bias, const float* __restrict__ resid,
    unsigned short* __restrict__ outB, float* __restrict__ outF,
    int M, int N, int K, int relu)
{
    __shared__ __align__(16) unsigned short As[128][32];
    __shared__ __align__(16) unsigned short Bs[128][32];
    const int tid = threadIdx.x;
    const int lane = tid & 63, wave = tid >> 6;
    const int quad = lane >> 4, l16 = lane & 15;
    const int wm = wave >> 1, wn = wave & 1;
    const int m0 = blockIdx.y * 128, n0 = blockIdx.x * 128;

    const f32x4 fzero = {0.f, 0.f, 0.f, 0.f};
    f32x4 acc[4][4];
#pragma unroll
    for (int i = 0; i < 4; ++i)
#pragma unroll
        for (int j = 0; j < 4; ++j) acc[i][j] = fzero;

    for (int k0 = 0; k0 < K; k0 += 32) {
#pragma unroll
        for (int p = 0; p < 2; ++p) {
            int c = tid + p * 256;
            int r = c >> 2, c8 = (c & 3) * 8;
            *(uint4*)&As[r][c8] = *(const uint4*)&A [(size_t)(m0 + r) * K + k0 + c8];
            *(uint4*)&Bs[r][c8] = *(const uint4*)&Bt[(size_t)(n0 + r) * K + k0 + c8];
        }
        __syncthreads();
        bf16x8 af[4], bfv[4];
#pragma unroll
        for (int i = 0; i < 4; ++i) af[i]  = ld_bf8(&As[wm * 64 + i * 16 + l16][quad * 8]);
#pragma unroll
        for (int j = 0; j < 4; ++j) bfv[j] = ld_bf8(&Bs[wn * 64 + j * 16 + l16][quad * 8]);
#pragma unroll
        for (int i = 0; i < 4; ++i)
#pragma unroll
            for (int j = 0; j < 4; ++j)
                acc[i][j] = __builtin_amdgcn_mfma_f32_16x16x32_bf16(af[i], bfv[j], acc[i][j], 0, 0, 0);
        __syncthreads();
    }
#pragma unroll
    for (int i = 0; i < 4; ++i)
#pragma unroll
        for (int j = 0; j < 4; ++j)
#pragma unroll
            for (int r = 0; r < 4; ++r) {
                const int gm = m0 + wm * 64 + i * 16 + quad * 4 + r;
                const int gn = n0 + wn * 64 + j * 16 + l16;
                float v = acc[i][j][r] + bias[gn];
                if (relu) v = fmaxf(v, 0.f);
                if (resid) v += resid[(size_t)gm * N + gn];
                if (outF) outF[(size_t)gm * N + gn] = v;
                if (outB) outB[(size_t)gm * N + gn] = f2bf(v);
            }
}

// ---------------- V^T extraction: qkv V-cols -> vtg[bh][64][4096] -------------------
__global__ __launch_bounds__(256) void vt_extract(
    const unsigned short* __restrict__ qkv, unsigned short* __restrict__ vtg)
{
    __shared__ unsigned short tile[64][72];
    const int bh = blockIdx.x, b = bh / HH, h = bh % HH;
    const int s0 = blockIdx.y * 64;
    const int tid = threadIdx.x;
#pragma unroll
    for (int p = 0; p < 2; ++p) {
        int idx = tid + p * 256;
        int r = idx >> 3, ch8 = (idx & 7) * 8;
        *(uint4*)&tile[r][ch8] =
            *(const uint4*)&qkv[(size_t)(b * SEQ + s0 + r) * 2304 + 1536 + h * 64 + ch8];
    }
    __syncthreads();
#pragma unroll
    for (int p = 0; p < 2; ++p) {
        int idx = tid + p * 256;
        int d = idx >> 3, sc = (idx & 7) * 8;
        unsigned short tmp[8];
#pragma unroll
        for (int j = 0; j < 8; ++j) tmp[j] = tile[sc + j][d];
        *(uint4*)&vtg[((size_t)bh * 64 + d) * SEQ + s0 + sc] = *(uint4*)tmp;
    }
}

// ---------------- flash attention v2: k-tile 128, 32 q rows/wave, bank-clean LDS ----
// Q pre-scaled by 0.125 (folded into wq/bq). scores = (q.k) * mask(fp32).
__global__ __launch_bounds__(256, 3) void flash_attn2(
    const unsigned short* __restrict__ qkv, const unsigned short* __restrict__ vtg,
    const float* __restrict__ mask, float* __restrict__ ctx)
{
    __shared__ __align__(16) unsigned short Ks[128][72];    // stride 36 dw == 4 mod 32
    __shared__ __align__(16) unsigned short Vt[64][136];    // stride 68 dw == 4 mod 32
    __shared__ __align__(16) unsigned short Ps[4][16][136]; // per-wave P staging
    const int tid = threadIdx.x;
    const int lane = tid & 63, wave = tid >> 6;
    const int quad = lane >> 4, l16 = lane & 15;
    const int bh = blockIdx.x, b = bh / HH, h = bh % HH;
    const int qbase = blockIdx.y * 128 + wave * 32;

    bf16x8 qf[2][2];
#pragma unroll
    for (int mt = 0; mt < 2; ++mt) {
        const size_t qrow = (size_t)(b * SEQ + qbase + mt * 16 + l16) * 2304 + h * 64;
        qf[mt][0] = ld_bf8(&qkv[qrow + quad * 8]);
        qf[mt][1] = ld_bf8(&qkv[qrow + 32 + quad * 8]);
    }
    const f32x4 fzero = {0.f, 0.f, 0.f, 0.f};
    float m_run[2][4], l_run[2][4];
    f32x4 o[2][4];
#pragma unroll
    for (int mt = 0; mt < 2; ++mt)
#pragma unroll
        for (int r = 0; r < 4; ++r) { m_run[mt][r] = -1e30f; l_run[mt][r] = 0.f; o[mt][r] = fzero; }

    const float* mbase = mask + (size_t)b * SEQ * SEQ;
    const unsigned short* kgbase = qkv + (size_t)b * SEQ * 2304 + 768 + h * 64;
    const unsigned short* vgbase = vtg + (size_t)bh * 64 * SEQ;

    for (int k0 = 0; k0 < SEQ; k0 += 128) {
        __syncthreads();
#pragma unroll
        for (int p = 0; p < 4; ++p) {           // K tile 128x64
            int idx = tid + p * 256;
            int row = idx >> 3, ch8 = (idx & 7) * 8;
            *(uint4*)&Ks[row][ch8] = *(const uint4*)&kgbase[(size_t)(k0 + row) * 2304 + ch8];
        }
#pragma unroll
        for (int p = 0; p < 4; ++p) {           // V^T tile 64x128
            int idx = tid + p * 256;
            int d = idx >> 4, ch8 = (idx & 15) * 8;
            *(uint4*)&Vt[d][ch8] = *(const uint4*)&vgbase[(size_t)d * SEQ + k0 + ch8];
        }
        __syncthreads();

#pragma unroll
        for (int mt = 0; mt < 2; ++mt) {
            // ---- S = Q K^T over 128 keys: 8 C-tiles of 16x16
            f32x4 st[8];
#pragma unroll
            for (int j = 0; j < 8; ++j) {
                st[j] = fzero;
                bf16x8 kf0 = ld_bf8(&Ks[j * 16 + l16][quad * 8]);
                st[j] = __builtin_amdgcn_mfma_f32_16x16x32_bf16(qf[mt][0], kf0, st[j], 0, 0, 0);
                bf16x8 kf1 = ld_bf8(&Ks[j * 16 + l16][32 + quad * 8]);
                st[j] = __builtin_amdgcn_mfma_f32_16x16x32_bf16(qf[mt][1], kf1, st[j], 0, 0, 0);
            }
            // ---- multiplicative mask (scores already carry 1/8 via Q)
            const int qr = qbase + mt * 16 + quad * 4;
#pragma unroll
            for (int r = 0; r < 4; ++r) {
                const float* mrow = &mbase[(size_t)(qr + r) * SEQ + k0 + l16];
#pragma unroll
                for (int j = 0; j < 8; ++j)
                    st[j][r] *= mrow[j * 16];
            }
            // ---- online softmax (state per quad row; reduce over l16 lanes)
            float alpha[4];
#pragma unroll
            for (int r = 0; r < 4; ++r) {
                float mx = st[0][r];
#pragma unroll
                for (int j = 1; j < 8; ++j) mx = fmaxf(mx, st[j][r]);
#pragma unroll
                for (int off = 1; off < 16; off <<= 1) mx = fmaxf(mx, __shfl_xor(mx, off));
                const float mnew = fmaxf(m_run[mt][r], mx);
                alpha[r] = __expf(m_run[mt][r] - mnew);
                float ssum = 0.f;
#pragma unroll
                for (int j = 0; j < 8; ++j) {
                    st[j][r] = __expf(st[j][r] - mnew);
                    ssum += st[j][r];
                }
#pragma unroll
                for (int off = 1; off < 16; off <<= 1) ssum += __shfl_xor(ssum, off);
                l_run[mt][r] = l_run[mt][r] * alpha[r] + ssum;
                m_run[mt][r] = mnew;
            }
#pragma unroll
            for (int t = 0; t < 4; ++t)
#pragma unroll
                for (int r = 0; r < 4; ++r) o[mt][t][r] *= alpha[r];
            // ---- P (C-layout) -> LDS -> A-layout (per-wave; in-order DS, no barrier)
#pragma unroll
            for (int j = 0; j < 8; ++j)
#pragma unroll
                for (int r = 0; r < 4; ++r)
                    Ps[wave][quad * 4 + r][j * 16 + l16] = f2bf(st[j][r]);
#pragma unroll
            for (int kk = 0; kk < 4; ++kk) {
                bf16x8 pf = ld_bf8(&Ps[wave][l16][kk * 32 + quad * 8]);
#pragma unroll
                for (int t = 0; t < 4; ++t) {
                    bf16x8 vf = ld_bf8(&Vt[t * 16 + l16][kk * 32 + quad * 8]);
                    o[mt][t] = __builtin_amdgcn_mfma_f32_16x16x32_bf16(pf, vf, o[mt][t], 0, 0, 0);
                }
            }
        }
    }
#pragma unroll
    for (int mt = 0; mt < 2; ++mt)
#pragma unroll
        for (int t = 0; t < 4; ++t)
#pragma unroll
            for (int r = 0; r < 4; ++r) {
                const int row = qbase + mt * 16 + quad * 4 + r;
                ctx[(size_t)(b * SEQ + row) * DD + h * 64 + t * 16 + l16] =
                    o[mt][t][r] / l_run[mt][r];
            }
}

// -----------------------------------------------------------------------------------
extern "C" void kernel_launch(void* const* d_in, const int* in_sizes, int n_in,
                              void* d_out, int out_size, void* d_ws, size_t ws_size,
                              hipStream_t stream)
{
    (void)in_sizes; (void)n_in; (void)out_size; (void)ws_size;
    const float* x      = (const float*)d_in[0];
    const float* mask   = (const float*)d_in[1];
    const float* wq     = (const float*)d_in[2];
    const float* bq     = (const float*)d_in[3];
    const float* wk     = (const float*)d_in[4];
    const float* bk     = (const float*)d_in[5];
    const float* wv     = (const float*)d_in[6];
    const float* bv     = (const float*)d_in[7];
    // d_in[8]=wo, d_in[9]=bo: reference never applies out_linear — intentionally unused
    const float* w1     = (const float*)d_in[10];
    const float* b1     = (const float*)d_in[11];
    const float* w2     = (const float*)d_in[12];
    const float* b2     = (const float*)d_in[13];
    const float* gamma1 = (const float*)d_in[14];
    const float* beta1  = (const float*)d_in[15];
    const float* gamma2 = (const float*)d_in[16];
    const float* beta2  = (const float*)d_in[17];
    float* out = (float*)d_out;

    char* ws = (char*)d_ws;
    size_t off = 0;
    auto take = [&](size_t bytes) -> char* {
        char* p = ws + off;
        off = (off + bytes + 255) & ~(size_t)255;
        return p;
    };
    unsigned short* wqkvT = (unsigned short*)take((size_t)2304 * 768 * 2);
    unsigned short* w1T   = (unsigned short*)take((size_t)3072 * 768 * 2);
    unsigned short* w2T   = (unsigned short*)take((size_t)768 * 3072 * 2);
    float*          bqkv  = (float*)take(2304 * 4);
    unsigned short* l12   = (unsigned short*)take((size_t)NTOK * DD * 2);
    unsigned short* qkv   = (unsigned short*)take((size_t)NTOK * 2304 * 2);
    float*          x1    = (float*)take((size_t)NTOK * DD * 4);
    // big region (50.3 MB): during attention = [ctx 25.2 MB | vtg 25.2 MB];
    // after LN2 it is reused whole as hb (FFN hidden). Stream-ordered, no overlap alive.
    char*           big   = take((size_t)NTOK * DFFN * 2);
    float*          ctx   = (float*)big;
    unsigned short* vtg   = (unsigned short*)(big + (size_t)NTOK * DD * 4);
    unsigned short* hb    = (unsigned short*)big;

    // weight prep (0.125 = 1/sqrt(DH) folded into wq/bq — exact, pow2)
    transpose_f32_to_bf16<<<dim3(24, 24), dim3(32, 8), 0, stream>>>(wq, wqkvT,                 768, 768, 0.125f);
    transpose_f32_to_bf16<<<dim3(24, 24), dim3(32, 8), 0, stream>>>(wk, wqkvT + 768 * 768,     768, 768, 1.0f);
    transpose_f32_to_bf16<<<dim3(24, 24), dim3(32, 8), 0, stream>>>(wv, wqkvT + 2 * 768 * 768, 768, 768, 1.0f);
    transpose_f32_to_bf16<<<dim3(96, 24), dim3(32, 8), 0, stream>>>(w1, w1T,                   768, 3072, 1.0f);
    transpose_f32_to_bf16<<<dim3(24, 96), dim3(32, 8), 0, stream>>>(w2, w2T,                   3072, 768, 1.0f);
    concat_bias<<<9, 256, 0, stream>>>(bq, bk, bv, bqkv);

    // LN1 -> l1 (bf16)
    ln_fused<<<NTOK, 256, 0, stream>>>(x, nullptr, gamma1, beta1, l12, nullptr);
    // fused QKV GEMM
    gemm_bf16<<<dim3(2304 / 128, NTOK / 128), 256, 0, stream>>>(
        l12, wqkvT, bqkv, nullptr, qkv, nullptr, NTOK, 2304, 768, 0);
    // V^T per head
    vt_extract<<<dim3(BB * HH, SEQ / 64), 256, 0, stream>>>(qkv, vtg);
    // flash attention v2 -> ctx fp32
    flash_attn2<<<dim3(BB * HH, SEQ / 128), 256, 0, stream>>>(qkv, vtg, mask, ctx);
    // x1 = x + ctx, LN2 -> l2 (bf16)
    ln_fused<<<NTOK, 256, 0, stream>>>(x, ctx, gamma2, beta2, l12, x1);
    // FFN1: relu(l2 @ w1 + b1) -> hb
    gemm_bf16<<<dim3(3072 / 128, NTOK / 128), 256, 0, stream>>>(
        l12, w1T, b1, nullptr, hb, nullptr, NTOK, 3072, 768, 1);
    // FFN2: hb @ w2 + b2 + x1 -> out
    gemm_bf16<<<dim3(768 / 128, NTOK / 128), 256, 0, stream>>>(
        hb, w2T, b2, x1, nullptr, out, NTOK, 768, 3072, 0);
}

// Round 3
// 865.028 us; speedup vs baseline: 1.3333x; 1.1954x over previous
//
#include <hip/hip_runtime.h>
#include <cstdint>
#include <cstddef>

#define BB   2
#define SEQ  4096
#define DD   768
#define HH   12
#define DHH  64
#define DFFN 3072
#define NTOK (BB*SEQ)

using bf16x8 = __attribute__((ext_vector_type(8))) __bf16;
using f32x4  = __attribute__((ext_vector_type(4))) float;
typedef unsigned int u32;

__device__ __forceinline__ unsigned short f2bf(float f) {
    unsigned u = __float_as_uint(f);
    u = u + 0x7FFFu + ((u >> 16) & 1u);
    return (unsigned short)(u >> 16);
}

__device__ __forceinline__ bf16x8 ld_bf8(const unsigned short* p) {
    return *(const bf16x8*)p;   // 16B aligned by construction
}

// async global->LDS, 16B per lane (m97 pattern; CK-style addrspace casts)
__device__ __forceinline__ void gl_lds16(const unsigned short* g, unsigned short* l) {
    __builtin_amdgcn_global_load_lds(
        (const __attribute__((address_space(1))) u32*)(uintptr_t)(const void*)g,
        (__attribute__((address_space(3))) u32*)(uintptr_t)(void*)l,
        16, 0, 0);
}

// ---------------- weight prep: fp32 [R][C] -> bf16 transposed [C][R], * scale -------
__global__ __launch_bounds__(256) void transpose_f32_to_bf16(
    const float* __restrict__ src, unsigned short* __restrict__ dst, int R, int C, float scale)
{
    __shared__ float tile[32][33];
    const int c0 = blockIdx.x * 32, r0 = blockIdx.y * 32;
    const int tx = threadIdx.x, ty = threadIdx.y;   // block (32,8)
#pragma unroll
    for (int i = 0; i < 32; i += 8)
        tile[ty + i][tx] = src[(size_t)(r0 + ty + i) * C + c0 + tx];
    __syncthreads();
#pragma unroll
    for (int i = 0; i < 32; i += 8)
        dst[(size_t)(c0 + ty + i) * R + r0 + tx] = f2bf(scale * tile[tx][ty + i]);
}

__global__ void concat_bias(const float* __restrict__ bq, const float* __restrict__ bk,
                            const float* __restrict__ bv, float* __restrict__ bqkv)
{
    int i = blockIdx.x * 256 + threadIdx.x;
    if (i < 3 * DD)
        bqkv[i] = (i < DD) ? bq[i] * 0.125f : (i < 2 * DD ? bk[i - DD] : bv[i - 2 * DD]);
}

// ---------------- mask scan: flag=1 iff any element != 1.0f -------------------------
__global__ __launch_bounds__(256) void mask_check(const float* __restrict__ mask, int* __restrict__ flag)
{
    const size_t n = (size_t)BB * SEQ * SEQ;
    const size_t stride = (size_t)gridDim.x * 1024;
    int bad = 0;
    for (size_t i = ((size_t)blockIdx.x * 256 + threadIdx.x) * 4; i < n; i += stride) {
        float4 v = *(const float4*)&mask[i];
        bad |= (v.x != 1.f) | (v.y != 1.f) | (v.z != 1.f) | (v.w != 1.f);
    }
    if (bad) atomicOr(flag, 1);   // wave-coalesced by compiler; rare path anyway
}

// ---------------- LayerNorm (torch.std semantics: ddof=1, denom = sigma + eps) ------
__global__ __launch_bounds__(256) void ln_fused(
    const float* __restrict__ x, const float* __restrict__ add,
    const float* __restrict__ gamma, const float* __restrict__ beta,
    unsigned short* __restrict__ out_ln, float* __restrict__ x1out)
{
    const int row = blockIdx.x, t = threadIdx.x;
    const size_t base = (size_t)row * DD;
    float v[3], s = 0.f, sq = 0.f;
#pragma unroll
    for (int p = 0; p < 3; ++p) {
        int idx = t + p * 256;
        float val = x[base + idx];
        if (add) val += add[base + idx];
        v[p] = val; s += val; sq += val * val;
    }
#pragma unroll
    for (int off = 1; off < 64; off <<= 1) {
        s  += __shfl_xor(s,  off);
        sq += __shfl_xor(sq, off);
    }
    __shared__ float red[8];
    const int wave = t >> 6;
    if ((t & 63) == 0) { red[wave] = s; red[4 + wave] = sq; }
    __syncthreads();
    s  = red[0] + red[1] + red[2] + red[3];
    sq = red[4] + red[5] + red[6] + red[7];
    const float mu   = s * (1.f / 768.f);
    const float var  = fmaxf((sq - 768.f * mu * mu) * (1.f / 767.f), 0.f);
    const float rstd = 1.f / (sqrtf(var) + 1e-6f);
#pragma unroll
    for (int p = 0; p < 3; ++p) {
        int idx = t + p * 256;
        if (x1out) x1out[base + idx] = v[p];
        out_ln[base + idx] = f2bf(gamma[idx] * (v[p] - mu) * rstd + beta[idx]);
    }
}

// ---------------- bf16 GEMM (m97 structure): async global->LDS staging --------------
__global__ __launch_bounds__(256) void gemm_bf16(
    const unsigned short* __restrict__ A, const unsigned short* __restrict__ Bt,
    const float* __restrict__ bias, const float* __restrict__ resid,
    unsigned short* __restrict__ outB, float* __restrict__ outF,
    int M, int N, int K, int relu)
{
    __shared__ __align__(16) unsigned short As[128][32];   // unpadded: global_load_lds needs contiguity
    __shared__ __align__(16) unsigned short Bs[128][32];
    const int tid = threadIdx.x;
    const int lane = tid & 63, wave = tid >> 6;
    const int quad = lane >> 4, l16 = lane & 15;
    const int wm = wave >> 1, wn = wave & 1;
    const int m0 = blockIdx.y * 128, n0 = blockIdx.x * 128;

    const f32x4 fzero = {0.f, 0.f, 0.f, 0.f};
    f32x4 acc[4][4];
#pragma unroll
    for (int i = 0; i < 4; ++i)
#pragma unroll
        for (int j = 0; j < 4; ++j) acc[i][j] = fzero;

    // LDS element offset for thread c is exactly c*8 => byte offset c*16 (lane-contiguous)
    const int r  = tid >> 2, c8 = (tid & 3) * 8;

    for (int k0 = 0; k0 < K; k0 += 32) {
        gl_lds16(&A [(size_t)(m0 + r) * K + k0 + c8],       &As[r][c8]);
        gl_lds16(&A [(size_t)(m0 + 64 + r) * K + k0 + c8],  &As[64 + r][c8]);
        gl_lds16(&Bt[(size_t)(n0 + r) * K + k0 + c8],       &Bs[r][c8]);
        gl_lds16(&Bt[(size_t)(n0 + 64 + r) * K + k0 + c8],  &Bs[64 + r][c8]);
        __syncthreads();   // compiler emits vmcnt(0) drain here (m97 structure)
        bf16x8 af[4], bfv[4];
#pragma unroll
        for (int i = 0; i < 4; ++i) af[i]  = ld_bf8(&As[wm * 64 + i * 16 + l16][quad * 8]);
#pragma unroll
        for (int j = 0; j < 4; ++j) bfv[j] = ld_bf8(&Bs[wn * 64 + j * 16 + l16][quad * 8]);
#pragma unroll
        for (int i = 0; i < 4; ++i)
#pragma unroll
            for (int j = 0; j < 4; ++j)
                acc[i][j] = __builtin_amdgcn_mfma_f32_16x16x32_bf16(af[i], bfv[j], acc[i][j], 0, 0, 0);
        __syncthreads();
    }
#pragma unroll
    for (int i = 0; i < 4; ++i)
#pragma unroll
        for (int j = 0; j < 4; ++j)
#pragma unroll
            for (int rr = 0; rr < 4; ++rr) {
                const int gm = m0 + wm * 64 + i * 16 + quad * 4 + rr;
                const int gn = n0 + wn * 64 + j * 16 + l16;
                float v = acc[i][j][rr] + bias[gn];
                if (relu) v = fmaxf(v, 0.f);
                if (resid) v += resid[(size_t)gm * N + gn];
                if (outF) outF[(size_t)gm * N + gn] = v;
                if (outB) outB[(size_t)gm * N + gn] = f2bf(v);
            }
}

// ---------------- V^T extraction: qkv V-cols -> vtg[bh][64][4096] -------------------
__global__ __launch_bounds__(256) void vt_extract(
    const unsigned short* __restrict__ qkv, unsigned short* __restrict__ vtg)
{
    __shared__ unsigned short tile[64][72];
    const int bh = blockIdx.x, b = bh / HH, h = bh % HH;
    const int s0 = blockIdx.y * 64;
    const int tid = threadIdx.x;
#pragma unroll
    for (int p = 0; p < 2; ++p) {
        int idx = tid + p * 256;
        int r = idx >> 3, ch8 = (idx & 7) * 8;
        *(uint4*)&tile[r][ch8] =
            *(const uint4*)&qkv[(size_t)(b * SEQ + s0 + r) * 2304 + 1536 + h * 64 + ch8];
    }
    __syncthreads();
#pragma unroll
    for (int p = 0; p < 2; ++p) {
        int idx = tid + p * 256;
        int d = idx >> 3, sc = (idx & 7) * 8;
        unsigned short tmp[8];
#pragma unroll
        for (int j = 0; j < 8; ++j) tmp[j] = tile[sc + j][d];
        *(uint4*)&vtg[((size_t)bh * 64 + d) * SEQ + s0 + sc] = *(uint4*)tmp;
    }
}

// ---------------- flash attention v3: mask fast-path, shared K-frags ----------------
// grid = (SEQ/128, BB*HH): adjacent blocks share one (b,h) K/V slab in L2.
__global__ __launch_bounds__(256, 3) void flash_attn3(
    const unsigned short* __restrict__ qkv, const unsigned short* __restrict__ vtg,
    const float* __restrict__ mask, const int* __restrict__ maskflag,
    float* __restrict__ ctx)
{
    __shared__ __align__(16) unsigned short Ks[128][72];    // stride 36 dw == 4 mod 32
    __shared__ __align__(16) unsigned short Vt[64][136];    // stride 68 dw == 4 mod 32
    __shared__ __align__(16) unsigned short Ps[4][16][136];
    const int tid = threadIdx.x;
    const int lane = tid & 63, wave = tid >> 6;
    const int quad = lane >> 4, l16 = lane & 15;
    const int bh = blockIdx.y, b = bh / HH, h = bh % HH;
    const int qbase = blockIdx.x * 128 + wave * 32;
    const int use_mask = *maskflag;

    bf16x8 qf[2][2];
#pragma unroll
    for (int mt = 0; mt < 2; ++mt) {
        const size_t qrow = (size_t)(b * SEQ + qbase + mt * 16 + l16) * 2304 + h * 64;
        qf[mt][0] = ld_bf8(&qkv[qrow + quad * 8]);
        qf[mt][1] = ld_bf8(&qkv[qrow + 32 + quad * 8]);
    }
    const f32x4 fzero = {0.f, 0.f, 0.f, 0.f};
    float m_run[2][4], l_run[2][4];
    f32x4 o[2][4];
#pragma unroll
    for (int mt = 0; mt < 2; ++mt)
#pragma unroll
        for (int r = 0; r < 4; ++r) { m_run[mt][r] = -1e30f; l_run[mt][r] = 0.f; o[mt][r] = fzero; }

    const float* mbase = mask + (size_t)b * SEQ * SEQ;
    const unsigned short* kgbase = qkv + (size_t)b * SEQ * 2304 + 768 + h * 64;
    const unsigned short* vgbase = vtg + (size_t)bh * 64 * SEQ;

    for (int k0 = 0; k0 < SEQ; k0 += 128) {
        __syncthreads();
#pragma unroll
        for (int p = 0; p < 4; ++p) {           // K tile 128x64
            int idx = tid + p * 256;
            int row = idx >> 3, ch8 = (idx & 7) * 8;
            *(uint4*)&Ks[row][ch8] = *(const uint4*)&kgbase[(size_t)(k0 + row) * 2304 + ch8];
        }
#pragma unroll
        for (int p = 0; p < 4; ++p) {           // V^T tile 64x128
            int idx = tid + p * 256;
            int d = idx >> 4, ch8 = (idx & 15) * 8;
            *(uint4*)&Vt[d][ch8] = *(const uint4*)&vgbase[(size_t)d * SEQ + k0 + ch8];
        }
        __syncthreads();

        // ---- S = Q K^T for BOTH q-subtiles; each kf feeds 2 MFMAs
        f32x4 st[2][8];
#pragma unroll
        for (int j = 0; j < 8; ++j) {
            bf16x8 kf0 = ld_bf8(&Ks[j * 16 + l16][quad * 8]);
            bf16x8 kf1 = ld_bf8(&Ks[j * 16 + l16][32 + quad * 8]);
            st[0][j] = __builtin_amdgcn_mfma_f32_16x16x32_bf16(qf[0][0], kf0, fzero, 0, 0, 0);
            st[0][j] = __builtin_amdgcn_mfma_f32_16x16x32_bf16(qf[0][1], kf1, st[0][j], 0, 0, 0);
            st[1][j] = __builtin_amdgcn_mfma_f32_16x16x32_bf16(qf[1][0], kf0, fzero, 0, 0, 0);
            st[1][j] = __builtin_amdgcn_mfma_f32_16x16x32_bf16(qf[1][1], kf1, st[1][j], 0, 0, 0);
        }
        if (use_mask) {                          // general path: multiplicative fp32 mask
#pragma unroll
            for (int mt = 0; mt < 2; ++mt) {
                const int qr = qbase + mt * 16 + quad * 4;
#pragma unroll
                for (int r = 0; r < 4; ++r) {
                    const float* mrow = &mbase[(size_t)(qr + r) * SEQ + k0 + l16];
#pragma unroll
                    for (int j = 0; j < 8; ++j)
                        st[mt][j][r] *= mrow[j * 16];
                }
            }
        }
        // ---- per-subtile online softmax + PV
#pragma unroll
        for (int mt = 0; mt < 2; ++mt) {
            float alpha[4];
#pragma unroll
            for (int r = 0; r < 4; ++r) {
                float mx = st[mt][0][r];
#pragma unroll
                for (int j = 1; j < 8; ++j) mx = fmaxf(mx, st[mt][j][r]);
#pragma unroll
                for (int off = 1; off < 16; off <<= 1) mx = fmaxf(mx, __shfl_xor(mx, off));
                const float mnew = fmaxf(m_run[mt][r], mx);
                alpha[r] = __expf(m_run[mt][r] - mnew);
                float ssum = 0.f;
#pragma unroll
                for (int j = 0; j < 8; ++j) {
                    st[mt][j][r] = __expf(st[mt][j][r] - mnew);
                    ssum += st[mt][j][r];
                }
#pragma unroll
                for (int off = 1; off < 16; off <<= 1) ssum += __shfl_xor(ssum, off);
                l_run[mt][r] = l_run[mt][r] * alpha[r] + ssum;
                m_run[mt][r] = mnew;
            }
#pragma unroll
            for (int t = 0; t < 4; ++t)
#pragma unroll
                for (int r = 0; r < 4; ++r) o[mt][t][r] *= alpha[r];
            // P (C-layout) -> per-wave LDS -> A-layout (in-order DS within wave)
#pragma unroll
            for (int j = 0; j < 8; ++j)
#pragma unroll
                for (int r = 0; r < 4; ++r)
                    Ps[wave][quad * 4 + r][j * 16 + l16] = f2bf(st[mt][j][r]);
#pragma unroll
            for (int kk = 0; kk < 4; ++kk) {
                bf16x8 pf = ld_bf8(&Ps[wave][l16][kk * 32 + quad * 8]);
#pragma unroll
                for (int t = 0; t < 4; ++t) {
                    bf16x8 vf = ld_bf8(&Vt[t * 16 + l16][kk * 32 + quad * 8]);
                    o[mt][t] = __builtin_amdgcn_mfma_f32_16x16x32_bf16(pf, vf, o[mt][t], 0, 0, 0);
                }
            }
        }
    }
#pragma unroll
    for (int mt = 0; mt < 2; ++mt)
#pragma unroll
        for (int t = 0; t < 4; ++t)
#pragma unroll
            for (int r = 0; r < 4; ++r) {
                const int row = qbase + mt * 16 + quad * 4 + r;
                ctx[(size_t)(b * SEQ + row) * DD + h * 64 + t * 16 + l16] =
                    o[mt][t][r] / l_run[mt][r];
            }
}

// -----------------------------------------------------------------------------------
extern "C" void kernel_launch(void* const* d_in, const int* in_sizes, int n_in,
                              void* d_out, int out_size, void* d_ws, size_t ws_size,
                              hipStream_t stream)
{
    (void)in_sizes; (void)n_in; (void)out_size; (void)ws_size;
    const float* x      = (const float*)d_in[0];
    const float* mask   = (const float*)d_in[1];
    const float* wq     = (const float*)d_in[2];
    const float* bq     = (const float*)d_in[3];
    const float* wk     = (const float*)d_in[4];
    const float* bk     = (const float*)d_in[5];
    const float* wv     = (const float*)d_in[6];
    const float* bv     = (const float*)d_in[7];
    // d_in[8]=wo, d_in[9]=bo: reference never applies out_linear — intentionally unused
    const float* w1     = (const float*)d_in[10];
    const float* b1     = (const float*)d_in[11];
    const float* w2     = (const float*)d_in[12];
    const float* b2     = (const float*)d_in[13];
    const float* gamma1 = (const float*)d_in[14];
    const float* beta1  = (const float*)d_in[15];
    const float* gamma2 = (const float*)d_in[16];
    const float* beta2  = (const float*)d_in[17];
    float* out = (float*)d_out;

    char* ws = (char*)d_ws;
    size_t off = 0;
    auto take = [&](size_t bytes) -> char* {
        char* p = ws + off;
        off = (off + bytes + 255) & ~(size_t)255;
        return p;
    };
    unsigned short* wqkvT = (unsigned short*)take((size_t)2304 * 768 * 2);
    unsigned short* w1T   = (unsigned short*)take((size_t)3072 * 768 * 2);
    unsigned short* w2T   = (unsigned short*)take((size_t)768 * 3072 * 2);
    float*          bqkv  = (float*)take(2304 * 4);
    int*            mflag = (int*)take(256);
    unsigned short* l12   = (unsigned short*)take((size_t)NTOK * DD * 2);
    unsigned short* qkv   = (unsigned short*)take((size_t)NTOK * 2304 * 2);
    float*          x1    = (float*)take((size_t)NTOK * DD * 4);
    // big region (50.3 MB): during attention = [ctx 25.2 MB | vtg 25.2 MB]; later hb.
    char*           big   = take((size_t)NTOK * DFFN * 2);
    float*          ctx   = (float*)big;
    unsigned short* vtg   = (unsigned short*)(big + (size_t)NTOK * DD * 4);
    unsigned short* hb    = (unsigned short*)big;

    hipMemsetAsync(mflag, 0, 4, stream);
    mask_check<<<2048, 256, 0, stream>>>(mask, mflag);

    // weight prep (0.125 = 1/sqrt(DH) folded into wq/bq — exact, pow2)
    transpose_f32_to_bf16<<<dim3(24, 24), dim3(32, 8), 0, stream>>>(wq, wqkvT,                 768, 768, 0.125f);
    transpose_f32_to_bf16<<<dim3(24, 24), dim3(32, 8), 0, stream>>>(wk, wqkvT + 768 * 768,     768, 768, 1.0f);
    transpose_f32_to_bf16<<<dim3(24, 24), dim3(32, 8), 0, stream>>>(wv, wqkvT + 2 * 768 * 768, 768, 768, 1.0f);
    transpose_f32_to_bf16<<<dim3(96, 24), dim3(32, 8), 0, stream>>>(w1, w1T,                   768, 3072, 1.0f);
    transpose_f32_to_bf16<<<dim3(24, 96), dim3(32, 8), 0, stream>>>(w2, w2T,                   3072, 768, 1.0f);
    concat_bias<<<9, 256, 0, stream>>>(bq, bk, bv, bqkv);

    // LN1 -> l1 (bf16)
    ln_fused<<<NTOK, 256, 0, stream>>>(x, nullptr, gamma1, beta1, l12, nullptr);
    // fused QKV GEMM
    gemm_bf16<<<dim3(2304 / 128, NTOK / 128), 256, 0, stream>>>(
        l12, wqkvT, bqkv, nullptr, qkv, nullptr, NTOK, 2304, 768, 0);
    // V^T per head
    vt_extract<<<dim3(BB * HH, SEQ / 64), 256, 0, stream>>>(qkv, vtg);
    // flash attention v3 -> ctx fp32
    flash_attn3<<<dim3(SEQ / 128, BB * HH), 256, 0, stream>>>(qkv, vtg, mask, mflag, ctx);
    // x1 = x + ctx, LN2 -> l2 (bf16)
    ln_fused<<<NTOK, 256, 0, stream>>>(x, ctx, gamma2, beta2, l12, x1);
    // FFN1: relu(l2 @ w1 + b1) -> hb
    gemm_bf16<<<dim3(3072 / 128, NTOK / 128), 256, 0, stream>>>(
        l12, w1T, b1, nullptr, hb, nullptr, NTOK, 3072, 768, 1);
    // FFN2: hb @ w2 + b2 + x1 -> out
    gemm_bf16<<<dim3(768 / 128, NTOK / 128), 256, 0, stream>>>(
        hb, w2T, b2, x1, nullptr, out, NTOK, 768, 3072, 0);
}

// Round 4
// 737.660 us; speedup vs baseline: 1.5636x; 1.1727x over previous
//
#include <hip/hip_runtime.h>
#include <cstdint>
#include <cstddef>

#define BB   2
#define SEQ  4096
#define DD   768
#define HH   12
#define DHH  64
#define DFFN 3072
#define NTOK (BB*SEQ)

using bf16x8 = __attribute__((ext_vector_type(8))) __bf16;
using f32x4  = __attribute__((ext_vector_type(4))) float;
typedef unsigned int u32;

__device__ __forceinline__ unsigned short f2bf(float f) {
    unsigned u = __float_as_uint(f);
    u = u + 0x7FFFu + ((u >> 16) & 1u);
    return (unsigned short)(u >> 16);
}

__device__ __forceinline__ bf16x8 ld_bf8(const unsigned short* p) {
    return *(const bf16x8*)p;   // 16B aligned by construction
}

// async global->LDS, 16B per lane (m97 pattern; CK-style addrspace casts)
__device__ __forceinline__ void gl_lds16(const unsigned short* g, unsigned short* l) {
    __builtin_amdgcn_global_load_lds(
        (const __attribute__((address_space(1))) u32*)(uintptr_t)(const void*)g,
        (__attribute__((address_space(3))) u32*)(uintptr_t)(void*)l,
        16, 0, 0);
}

// ---- DPP 16-lane reductions (row_ror 1/2/4/8; rows=16-lane groups, VALU pipe only)
template <int N>
__device__ __forceinline__ float dpp_ror(float x) {
    return __int_as_float(__builtin_amdgcn_update_dpp(
        0, __float_as_int(x), 0x120 | N, 0xf, 0xf, false));
}
__device__ __forceinline__ float rowmax16(float x) {
    x = fmaxf(x, dpp_ror<1>(x));
    x = fmaxf(x, dpp_ror<2>(x));
    x = fmaxf(x, dpp_ror<4>(x));
    x = fmaxf(x, dpp_ror<8>(x));
    return x;
}
__device__ __forceinline__ float rowsum16(float x) {
    x += dpp_ror<1>(x);
    x += dpp_ror<2>(x);
    x += dpp_ror<4>(x);
    x += dpp_ror<8>(x);
    return x;
}

// ---------------- weight prep: fp32 [R][C] -> bf16 transposed [C][R], * scale -------
__global__ __launch_bounds__(256) void transpose_f32_to_bf16(
    const float* __restrict__ src, unsigned short* __restrict__ dst, int R, int C, float scale)
{
    __shared__ float tile[32][33];
    const int c0 = blockIdx.x * 32, r0 = blockIdx.y * 32;
    const int tx = threadIdx.x, ty = threadIdx.y;   // block (32,8)
#pragma unroll
    for (int i = 0; i < 32; i += 8)
        tile[ty + i][tx] = src[(size_t)(r0 + ty + i) * C + c0 + tx];
    __syncthreads();
#pragma unroll
    for (int i = 0; i < 32; i += 8)
        dst[(size_t)(c0 + ty + i) * R + r0 + tx] = f2bf(scale * tile[tx][ty + i]);
}

__global__ void concat_bias(const float* __restrict__ bq, const float* __restrict__ bk,
                            const float* __restrict__ bv, float* __restrict__ bqkv)
{
    int i = blockIdx.x * 256 + threadIdx.x;
    if (i < 3 * DD)
        bqkv[i] = (i < DD) ? bq[i] * 0.125f : (i < 2 * DD ? bk[i - DD] : bv[i - 2 * DD]);
}

// ---------------- mask scan: flag=1 iff any element != 1.0f -------------------------
__global__ __launch_bounds__(256) void mask_check(const float* __restrict__ mask, int* __restrict__ flag)
{
    const size_t n = (size_t)BB * SEQ * SEQ;
    const size_t stride = (size_t)gridDim.x * 1024;
    int bad = 0;
    for (size_t i = ((size_t)blockIdx.x * 256 + threadIdx.x) * 4; i < n; i += stride) {
        float4 v = *(const float4*)&mask[i];
        bad |= (v.x != 1.f) | (v.y != 1.f) | (v.z != 1.f) | (v.w != 1.f);
    }
    if (bad) atomicOr(flag, 1);
}

// ---------------- LayerNorm (torch.std semantics: ddof=1, denom = sigma + eps) ------
__global__ __launch_bounds__(256) void ln_fused(
    const float* __restrict__ x, const float* __restrict__ add,
    const float* __restrict__ gamma, const float* __restrict__ beta,
    unsigned short* __restrict__ out_ln, float* __restrict__ x1out)
{
    const int row = blockIdx.x, t = threadIdx.x;
    const size_t base = (size_t)row * DD;
    float v[3], s = 0.f, sq = 0.f;
#pragma unroll
    for (int p = 0; p < 3; ++p) {
        int idx = t + p * 256;
        float val = x[base + idx];
        if (add) val += add[base + idx];
        v[p] = val; s += val; sq += val * val;
    }
#pragma unroll
    for (int off = 1; off < 64; off <<= 1) {
        s  += __shfl_xor(s,  off);
        sq += __shfl_xor(sq, off);
    }
    __shared__ float red[8];
    const int wave = t >> 6;
    if ((t & 63) == 0) { red[wave] = s; red[4 + wave] = sq; }
    __syncthreads();
    s  = red[0] + red[1] + red[2] + red[3];
    sq = red[4] + red[5] + red[6] + red[7];
    const float mu   = s * (1.f / 768.f);
    const float var  = fmaxf((sq - 768.f * mu * mu) * (1.f / 767.f), 0.f);
    const float rstd = 1.f / (sqrtf(var) + 1e-6f);
#pragma unroll
    for (int p = 0; p < 3; ++p) {
        int idx = t + p * 256;
        if (x1out) x1out[base + idx] = v[p];
        out_ln[base + idx] = f2bf(gamma[idx] * (v[p] - mu) * rstd + beta[idx]);
    }
}

// ---------------- bf16 GEMM (m97 structure): async global->LDS staging --------------
__global__ __launch_bounds__(256) void gemm_bf16(
    const unsigned short* __restrict__ A, const unsigned short* __restrict__ Bt,
    const float* __restrict__ bias, const float* __restrict__ resid,
    unsigned short* __restrict__ outB, float* __restrict__ outF,
    int M, int N, int K, int relu)
{
    __shared__ __align__(16) unsigned short As[128][32];
    __shared__ __align__(16) unsigned short Bs[128][32];
    const int tid = threadIdx.x;
    const int lane = tid & 63, wave = tid >> 6;
    const int quad = lane >> 4, l16 = lane & 15;
    const int wm = wave >> 1, wn = wave & 1;
    const int m0 = blockIdx.y * 128, n0 = blockIdx.x * 128;

    const f32x4 fzero = {0.f, 0.f, 0.f, 0.f};
    f32x4 acc[4][4];
#pragma unroll
    for (int i = 0; i < 4; ++i)
#pragma unroll
        for (int j = 0; j < 4; ++j) acc[i][j] = fzero;

    const int r  = tid >> 2, c8 = (tid & 3) * 8;

    for (int k0 = 0; k0 < K; k0 += 32) {
        gl_lds16(&A [(size_t)(m0 + r) * K + k0 + c8],       &As[r][c8]);
        gl_lds16(&A [(size_t)(m0 + 64 + r) * K + k0 + c8],  &As[64 + r][c8]);
        gl_lds16(&Bt[(size_t)(n0 + r) * K + k0 + c8],       &Bs[r][c8]);
        gl_lds16(&Bt[(size_t)(n0 + 64 + r) * K + k0 + c8],  &Bs[64 + r][c8]);
        __syncthreads();
        bf16x8 af[4], bfv[4];
#pragma unroll
        for (int i = 0; i < 4; ++i) af[i]  = ld_bf8(&As[wm * 64 + i * 16 + l16][quad * 8]);
#pragma unroll
        for (int j = 0; j < 4; ++j) bfv[j] = ld_bf8(&Bs[wn * 64 + j * 16 + l16][quad * 8]);
#pragma unroll
        for (int i = 0; i < 4; ++i)
#pragma unroll
            for (int j = 0; j < 4; ++j)
                acc[i][j] = __builtin_amdgcn_mfma_f32_16x16x32_bf16(af[i], bfv[j], acc[i][j], 0, 0, 0);
        __syncthreads();
    }
#pragma unroll
    for (int i = 0; i < 4; ++i)
#pragma unroll
        for (int j = 0; j < 4; ++j)
#pragma unroll
            for (int rr = 0; rr < 4; ++rr) {
                const int gm = m0 + wm * 64 + i * 16 + quad * 4 + rr;
                const int gn = n0 + wn * 64 + j * 16 + l16;
                float v = acc[i][j][rr] + bias[gn];
                if (relu) v = fmaxf(v, 0.f);
                if (resid) v += resid[(size_t)gm * N + gn];
                if (outF) outF[(size_t)gm * N + gn] = v;
                if (outB) outB[(size_t)gm * N + gn] = f2bf(v);
            }
}

// ---------------- V^T extraction: qkv V-cols -> vtg[bh][64][4096] -------------------
__global__ __launch_bounds__(256) void vt_extract(
    const unsigned short* __restrict__ qkv, unsigned short* __restrict__ vtg)
{
    __shared__ unsigned short tile[64][72];
    const int bh = blockIdx.x, b = bh / HH, h = bh % HH;
    const int s0 = blockIdx.y * 64;
    const int tid = threadIdx.x;
#pragma unroll
    for (int p = 0; p < 2; ++p) {
        int idx = tid + p * 256;
        int r = idx >> 3, ch8 = (idx & 7) * 8;
        *(uint4*)&tile[r][ch8] =
            *(const uint4*)&qkv[(size_t)(b * SEQ + s0 + r) * 2304 + 1536 + h * 64 + ch8];
    }
    __syncthreads();
#pragma unroll
    for (int p = 0; p < 2; ++p) {
        int idx = tid + p * 256;
        int d = idx >> 3, sc = (idx & 7) * 8;
        unsigned short tmp[8];
#pragma unroll
        for (int j = 0; j < 8; ++j) tmp[j] = tile[sc + j][d];
        *(uint4*)&vtg[((size_t)bh * 64 + d) * SEQ + s0 + sc] = *(uint4*)tmp;
    }
}

// ---------------- flash attention v4: no spills, DPP softmax, shared V-frags --------
// grid = (SEQ/128, BB*HH): adjacent blocks share one (b,h) K/V slab in L2.
__global__ __launch_bounds__(256, 2) void flash_attn4(
    const unsigned short* __restrict__ qkv, const unsigned short* __restrict__ vtg,
    const float* __restrict__ mask, const int* __restrict__ maskflag,
    float* __restrict__ ctx)
{
    __shared__ __align__(16) unsigned short Ks[128][72];       // stride 36 dw == 4 mod 32
    __shared__ __align__(16) unsigned short Vt[64][136];       // stride 68 dw == 4 mod 32
    __shared__ __align__(16) unsigned short Ps[4][2][16][136]; // both q-subtiles staged
    const int tid = threadIdx.x;
    const int lane = tid & 63, wave = tid >> 6;
    const int quad = lane >> 4, l16 = lane & 15;
    const int bh = blockIdx.y, b = bh / HH, h = bh % HH;
    const int qbase = blockIdx.x * 128 + wave * 32;
    const int use_mask = *maskflag;

    bf16x8 qf[2][2];
#pragma unroll
    for (int mt = 0; mt < 2; ++mt) {
        const size_t qrow = (size_t)(b * SEQ + qbase + mt * 16 + l16) * 2304 + h * 64;
        qf[mt][0] = ld_bf8(&qkv[qrow + quad * 8]);
        qf[mt][1] = ld_bf8(&qkv[qrow + 32 + quad * 8]);
    }
    const f32x4 fzero = {0.f, 0.f, 0.f, 0.f};
    float m_run[2][4], l_run[2][4];
    f32x4 o[2][4];
#pragma unroll
    for (int mt = 0; mt < 2; ++mt)
#pragma unroll
        for (int r = 0; r < 4; ++r) { m_run[mt][r] = -1e30f; l_run[mt][r] = 0.f; o[mt][r] = fzero; }

    const float* mbase = mask + (size_t)b * SEQ * SEQ;
    const unsigned short* kgbase = qkv + (size_t)b * SEQ * 2304 + 768 + h * 64;
    const unsigned short* vgbase = vtg + (size_t)bh * 64 * SEQ;

    for (int k0 = 0; k0 < SEQ; k0 += 128) {
        __syncthreads();
#pragma unroll
        for (int p = 0; p < 4; ++p) {           // K tile 128x64
            int idx = tid + p * 256;
            int row = idx >> 3, ch8 = (idx & 7) * 8;
            *(uint4*)&Ks[row][ch8] = *(const uint4*)&kgbase[(size_t)(k0 + row) * 2304 + ch8];
        }
#pragma unroll
        for (int p = 0; p < 4; ++p) {           // V^T tile 64x128
            int idx = tid + p * 256;
            int d = idx >> 4, ch8 = (idx & 15) * 8;
            *(uint4*)&Vt[d][ch8] = *(const uint4*)&vgbase[(size_t)d * SEQ + k0 + ch8];
        }
        __syncthreads();

        // ---- S = Q K^T for BOTH q-subtiles; each kf feeds 2 MFMAs
        f32x4 st[2][8];
#pragma unroll
        for (int j = 0; j < 8; ++j) {
            bf16x8 kf0 = ld_bf8(&Ks[j * 16 + l16][quad * 8]);
            bf16x8 kf1 = ld_bf8(&Ks[j * 16 + l16][32 + quad * 8]);
            st[0][j] = __builtin_amdgcn_mfma_f32_16x16x32_bf16(qf[0][0], kf0, fzero, 0, 0, 0);
            st[0][j] = __builtin_amdgcn_mfma_f32_16x16x32_bf16(qf[0][1], kf1, st[0][j], 0, 0, 0);
            st[1][j] = __builtin_amdgcn_mfma_f32_16x16x32_bf16(qf[1][0], kf0, fzero, 0, 0, 0);
            st[1][j] = __builtin_amdgcn_mfma_f32_16x16x32_bf16(qf[1][1], kf1, st[1][j], 0, 0, 0);
        }
        if (use_mask) {                          // general path: multiplicative fp32 mask
#pragma unroll
            for (int mt = 0; mt < 2; ++mt) {
                const int qr = qbase + mt * 16 + quad * 4;
#pragma unroll
                for (int r = 0; r < 4; ++r) {
                    const float* mrow = &mbase[(size_t)(qr + r) * SEQ + k0 + l16];
#pragma unroll
                    for (int j = 0; j < 8; ++j)
                        st[mt][j][r] *= mrow[j * 16];
                }
            }
        }
        // ---- online softmax per subtile (DPP row reductions, VALU-only), stage P
#pragma unroll
        for (int mt = 0; mt < 2; ++mt) {
            float alpha[4];
#pragma unroll
            for (int r = 0; r < 4; ++r) {
                float mx = st[mt][0][r];
#pragma unroll
                for (int j = 1; j < 8; ++j) mx = fmaxf(mx, st[mt][j][r]);
                mx = rowmax16(mx);
                const float mnew = fmaxf(m_run[mt][r], mx);
                alpha[r] = __expf(m_run[mt][r] - mnew);
                float ssum = 0.f;
#pragma unroll
                for (int j = 0; j < 8; ++j) {
                    st[mt][j][r] = __expf(st[mt][j][r] - mnew);
                    ssum += st[mt][j][r];
                }
                ssum = rowsum16(ssum);
                l_run[mt][r] = l_run[mt][r] * alpha[r] + ssum;
                m_run[mt][r] = mnew;
            }
#pragma unroll
            for (int t = 0; t < 4; ++t)
#pragma unroll
                for (int r = 0; r < 4; ++r) o[mt][t][r] *= alpha[r];
#pragma unroll
            for (int j = 0; j < 8; ++j)
#pragma unroll
                for (int r = 0; r < 4; ++r)
                    Ps[wave][mt][quad * 4 + r][j * 16 + l16] = f2bf(st[mt][j][r]);
        }
        // ---- PV for both subtiles; each vf feeds 2 MFMAs (in-order DS within wave)
#pragma unroll
        for (int kk = 0; kk < 4; ++kk) {
            bf16x8 pf0 = ld_bf8(&Ps[wave][0][l16][kk * 32 + quad * 8]);
            bf16x8 pf1 = ld_bf8(&Ps[wave][1][l16][kk * 32 + quad * 8]);
#pragma unroll
            for (int t = 0; t < 4; ++t) {
                bf16x8 vf = ld_bf8(&Vt[t * 16 + l16][kk * 32 + quad * 8]);
                o[0][t] = __builtin_amdgcn_mfma_f32_16x16x32_bf16(pf0, vf, o[0][t], 0, 0, 0);
                o[1][t] = __builtin_amdgcn_mfma_f32_16x16x32_bf16(pf1, vf, o[1][t], 0, 0, 0);
            }
        }
    }
#pragma unroll
    for (int mt = 0; mt < 2; ++mt)
#pragma unroll
        for (int t = 0; t < 4; ++t)
#pragma unroll
            for (int r = 0; r < 4; ++r) {
                const int row = qbase + mt * 16 + quad * 4 + r;
                ctx[(size_t)(b * SEQ + row) * DD + h * 64 + t * 16 + l16] =
                    o[mt][t][r] / l_run[mt][r];
            }
}

// -----------------------------------------------------------------------------------
extern "C" void kernel_launch(void* const* d_in, const int* in_sizes, int n_in,
                              void* d_out, int out_size, void* d_ws, size_t ws_size,
                              hipStream_t stream)
{
    (void)in_sizes; (void)n_in; (void)out_size; (void)ws_size;
    const float* x      = (const float*)d_in[0];
    const float* mask   = (const float*)d_in[1];
    const float* wq     = (const float*)d_in[2];
    const float* bq     = (const float*)d_in[3];
    const float* wk     = (const float*)d_in[4];
    const float* bk     = (const float*)d_in[5];
    const float* wv     = (const float*)d_in[6];
    const float* bv     = (const float*)d_in[7];
    // d_in[8]=wo, d_in[9]=bo: reference never applies out_linear — intentionally unused
    const float* w1     = (const float*)d_in[10];
    const float* b1     = (const float*)d_in[11];
    const float* w2     = (const float*)d_in[12];
    const float* b2     = (const float*)d_in[13];
    const float* gamma1 = (const float*)d_in[14];
    const float* beta1  = (const float*)d_in[15];
    const float* gamma2 = (const float*)d_in[16];
    const float* beta2  = (const float*)d_in[17];
    float* out = (float*)d_out;

    char* ws = (char*)d_ws;
    size_t off = 0;
    auto take = [&](size_t bytes) -> char* {
        char* p = ws + off;
        off = (off + bytes + 255) & ~(size_t)255;
        return p;
    };
    unsigned short* wqkvT = (unsigned short*)take((size_t)2304 * 768 * 2);
    unsigned short* w1T   = (unsigned short*)take((size_t)3072 * 768 * 2);
    unsigned short* w2T   = (unsigned short*)take((size_t)768 * 3072 * 2);
    float*          bqkv  = (float*)take(2304 * 4);
    int*            mflag = (int*)take(256);
    unsigned short* l12   = (unsigned short*)take((size_t)NTOK * DD * 2);
    unsigned short* qkv   = (unsigned short*)take((size_t)NTOK * 2304 * 2);
    float*          x1    = (float*)take((size_t)NTOK * DD * 4);
    // big region (50.3 MB): during attention = [ctx 25.2 MB | vtg 25.2 MB]; later hb.
    char*           big   = take((size_t)NTOK * DFFN * 2);
    float*          ctx   = (float*)big;
    unsigned short* vtg   = (unsigned short*)(big + (size_t)NTOK * DD * 4);
    unsigned short* hb    = (unsigned short*)big;

    hipMemsetAsync(mflag, 0, 4, stream);
    mask_check<<<2048, 256, 0, stream>>>(mask, mflag);

    // weight prep (0.125 = 1/sqrt(DH) folded into wq/bq — exact, pow2)
    transpose_f32_to_bf16<<<dim3(24, 24), dim3(32, 8), 0, stream>>>(wq, wqkvT,                 768, 768, 0.125f);
    transpose_f32_to_bf16<<<dim3(24, 24), dim3(32, 8), 0, stream>>>(wk, wqkvT + 768 * 768,     768, 768, 1.0f);
    transpose_f32_to_bf16<<<dim3(24, 24), dim3(32, 8), 0, stream>>>(wv, wqkvT + 2 * 768 * 768, 768, 768, 1.0f);
    transpose_f32_to_bf16<<<dim3(96, 24), dim3(32, 8), 0, stream>>>(w1, w1T,                   768, 3072, 1.0f);
    transpose_f32_to_bf16<<<dim3(24, 96), dim3(32, 8), 0, stream>>>(w2, w2T,                   3072, 768, 1.0f);
    concat_bias<<<9, 256, 0, stream>>>(bq, bk, bv, bqkv);

    // LN1 -> l1 (bf16)
    ln_fused<<<NTOK, 256, 0, stream>>>(x, nullptr, gamma1, beta1, l12, nullptr);
    // fused QKV GEMM
    gemm_bf16<<<dim3(2304 / 128, NTOK / 128), 256, 0, stream>>>(
        l12, wqkvT, bqkv, nullptr, qkv, nullptr, NTOK, 2304, 768, 0);
    // V^T per head
    vt_extract<<<dim3(BB * HH, SEQ / 64), 256, 0, stream>>>(qkv, vtg);
    // flash attention v4 -> ctx fp32
    flash_attn4<<<dim3(SEQ / 128, BB * HH), 256, 0, stream>>>(qkv, vtg, mask, mflag, ctx);
    // x1 = x + ctx, LN2 -> l2 (bf16)
    ln_fused<<<NTOK, 256, 0, stream>>>(x, ctx, gamma2, beta2, l12, x1);
    // FFN1: relu(l2 @ w1 + b1) -> hb
    gemm_bf16<<<dim3(3072 / 128, NTOK / 128), 256, 0, stream>>>(
        l12, w1T, b1, nullptr, hb, nullptr, NTOK, 3072, 768, 1);
    // FFN2: hb @ w2 + b2 + x1 -> out
    gemm_bf16<<<dim3(768 / 128, NTOK / 128), 256, 0, stream>>>(
        hb, w2T, b2, x1, nullptr, out, NTOK, 768, 3072, 0);
}

// Round 6
// 670.387 us; speedup vs baseline: 1.7205x; 1.1003x over previous
//
#include <hip/hip_runtime.h>
#include <cstdint>
#include <cstddef>

#define BB   2
#define SEQ  4096
#define DD   768
#define HH   12
#define DHH  64
#define DFFN 3072
#define NTOK (BB*SEQ)

using bf16x8 = __attribute__((ext_vector_type(8))) __bf16;
using f32x4  = __attribute__((ext_vector_type(4))) float;
typedef unsigned int u32;

#define QK_SCALE 0.18033688011112042f   // 0.125 * log2(e): folds 1/sqrt(DH) AND e->2 base swap

__device__ __forceinline__ float fast_exp2(float x) {
    return __builtin_amdgcn_exp2f(x);   // v_exp_f32: hw computes 2^x
}

__device__ __forceinline__ unsigned short f2bf(float f) {
    unsigned u = __float_as_uint(f);
    u = u + 0x7FFFu + ((u >> 16) & 1u);
    return (unsigned short)(u >> 16);
}
// truncating bf16 (1 VALU op; rel err <2^-8, fine for P matrix)
__device__ __forceinline__ unsigned short f2bf_trunc(float f) {
    return (unsigned short)(__float_as_uint(f) >> 16);
}

__device__ __forceinline__ bf16x8 ld_bf8(const unsigned short* p) {
    return *(const bf16x8*)p;   // 16B aligned by construction
}

// async global->LDS, 16B per lane (m97 pattern)
__device__ __forceinline__ void gl_lds16(const unsigned short* g, unsigned short* l) {
    __builtin_amdgcn_global_load_lds(
        (const __attribute__((address_space(1))) u32*)(uintptr_t)(const void*)g,
        (__attribute__((address_space(3))) u32*)(uintptr_t)(void*)l,
        16, 0, 0);
}

// ---- DPP 16-lane reductions (row_ror 1/2/4/8; VALU pipe only)
template <int N>
__device__ __forceinline__ float dpp_ror(float x) {
    return __int_as_float(__builtin_amdgcn_update_dpp(
        0, __float_as_int(x), 0x120 | N, 0xf, 0xf, false));
}
__device__ __forceinline__ float rowmax16(float x) {
    x = fmaxf(x, dpp_ror<1>(x));
    x = fmaxf(x, dpp_ror<2>(x));
    x = fmaxf(x, dpp_ror<4>(x));
    x = fmaxf(x, dpp_ror<8>(x));
    return x;
}
__device__ __forceinline__ float rowsum16(float x) {
    x += dpp_ror<1>(x);
    x += dpp_ror<2>(x);
    x += dpp_ror<4>(x);
    x += dpp_ror<8>(x);
    return x;
}

// ---------------- weight prep: fp32 [R][C] -> bf16 transposed [C][R], * scale -------
__global__ __launch_bounds__(256) void transpose_f32_to_bf16(
    const float* __restrict__ src, unsigned short* __restrict__ dst, int R, int C, float scale)
{
    __shared__ float tile[32][33];
    const int c0 = blockIdx.x * 32, r0 = blockIdx.y * 32;
    const int tx = threadIdx.x, ty = threadIdx.y;   // block (32,8)
#pragma unroll
    for (int i = 0; i < 32; i += 8)
        tile[ty + i][tx] = src[(size_t)(r0 + ty + i) * C + c0 + tx];
    __syncthreads();
#pragma unroll
    for (int i = 0; i < 32; i += 8)
        dst[(size_t)(c0 + ty + i) * R + r0 + tx] = f2bf(scale * tile[tx][ty + i]);
}

__global__ void concat_bias(const float* __restrict__ bq, const float* __restrict__ bk,
                            const float* __restrict__ bv, float* __restrict__ bqkv)
{
    int i = blockIdx.x * 256 + threadIdx.x;
    if (i < 3 * DD)
        bqkv[i] = (i < DD) ? bq[i] * QK_SCALE : (i < 2 * DD ? bk[i - DD] : bv[i - 2 * DD]);
}

// ---------------- mask scan: flag=1 iff any element != 1.0f -------------------------
__global__ __launch_bounds__(256) void mask_check(const float* __restrict__ mask, int* __restrict__ flag)
{
    const size_t n = (size_t)BB * SEQ * SEQ;
    const size_t stride = (size_t)gridDim.x * 1024;
    int bad = 0;
    for (size_t i = ((size_t)blockIdx.x * 256 + threadIdx.x) * 4; i < n; i += stride) {
        float4 v = *(const float4*)&mask[i];
        bad |= (v.x != 1.f) | (v.y != 1.f) | (v.z != 1.f) | (v.w != 1.f);
    }
    if (bad) atomicOr(flag, 1);
}

// ---------------- LayerNorm (torch.std semantics: ddof=1, denom = sigma + eps) ------
__global__ __launch_bounds__(256) void ln_fused(
    const float* __restrict__ x, const float* __restrict__ add,
    const float* __restrict__ gamma, const float* __restrict__ beta,
    unsigned short* __restrict__ out_ln, float* __restrict__ x1out)
{
    const int row = blockIdx.x, t = threadIdx.x;
    const size_t base = (size_t)row * DD;
    float v[3], s = 0.f, sq = 0.f;
#pragma unroll
    for (int p = 0; p < 3; ++p) {
        int idx = t + p * 256;
        float val = x[base + idx];
        if (add) val += add[base + idx];
        v[p] = val; s += val; sq += val * val;
    }
#pragma unroll
    for (int off = 1; off < 64; off <<= 1) {
        s  += __shfl_xor(s,  off);
        sq += __shfl_xor(sq, off);
    }
    __shared__ float red[8];
    const int wave = t >> 6;
    if ((t & 63) == 0) { red[wave] = s; red[4 + wave] = sq; }
    __syncthreads();
    s  = red[0] + red[1] + red[2] + red[3];
    sq = red[4] + red[5] + red[6] + red[7];
    const float mu   = s * (1.f / 768.f);
    const float var  = fmaxf((sq - 768.f * mu * mu) * (1.f / 767.f), 0.f);
    const float rstd = 1.f / (sqrtf(var) + 1e-6f);
#pragma unroll
    for (int p = 0; p < 3; ++p) {
        int idx = t + p * 256;
        if (x1out) x1out[base + idx] = v[p];
        out_ln[base + idx] = f2bf(gamma[idx] * (v[p] - mu) * rstd + beta[idx]);
    }
}

// ---------------- bf16 GEMM: BK=64, XOR-swizzled LDS (conflict-free frag reads) -----
// Swizzle: LDS slot (row, cg) holds global granule (cg ^ (row&7)); reads un-permute.
__global__ __launch_bounds__(256) void gemm_bf16(
    const unsigned short* __restrict__ A, const unsigned short* __restrict__ Bt,
    const float* __restrict__ bias, const float* __restrict__ resid,
    unsigned short* __restrict__ outB, float* __restrict__ outF,
    int M, int N, int K, int relu)
{
    __shared__ __align__(16) unsigned short As[128][64];
    __shared__ __align__(16) unsigned short Bs[128][64];
    const int tid = threadIdx.x;
    const int lane = tid & 63, wave = tid >> 6;
    const int quad = lane >> 4, l16 = lane & 15;
    const int wm = wave >> 1, wn = wave & 1;
    const int m0 = blockIdx.y * 128, n0 = blockIdx.x * 128;

    const f32x4 fzero = {0.f, 0.f, 0.f, 0.f};
    f32x4 acc[4][4];
#pragma unroll
    for (int i = 0; i < 4; ++i)
#pragma unroll
        for (int j = 0; j < 4; ++j) acc[i][j] = fzero;

    const int r  = tid >> 3;            // 0..31: LDS row slot
    const int cg = tid & 7;             // 0..7 : LDS granule slot (16B)

    for (int k0 = 0; k0 < K; k0 += 64) {
#pragma unroll
        for (int rr = 0; rr < 4; ++rr) {
            const int row = r + rr * 32;
            const int gc8 = (cg ^ (row & 7)) * 8;   // which global granule lives here
            gl_lds16(&A [(size_t)(m0 + row) * K + k0 + gc8], &As[row][cg * 8]);
            gl_lds16(&Bt[(size_t)(n0 + row) * K + k0 + gc8], &Bs[row][cg * 8]);
        }
        __syncthreads();
#pragma unroll
        for (int ks = 0; ks < 2; ++ks) {
            bf16x8 af[4], bfv[4];
#pragma unroll
            for (int i = 0; i < 4; ++i) {
                const int row = wm * 64 + i * 16 + l16;
                af[i] = ld_bf8(&As[row][((ks * 4 + quad) ^ (row & 7)) * 8]);
            }
#pragma unroll
            for (int j = 0; j < 4; ++j) {
                const int row = wn * 64 + j * 16 + l16;
                bfv[j] = ld_bf8(&Bs[row][((ks * 4 + quad) ^ (row & 7)) * 8]);
            }
#pragma unroll
            for (int i = 0; i < 4; ++i)
#pragma unroll
                for (int j = 0; j < 4; ++j)
                    acc[i][j] = __builtin_amdgcn_mfma_f32_16x16x32_bf16(af[i], bfv[j], acc[i][j], 0, 0, 0);
        }
        __syncthreads();
    }
#pragma unroll
    for (int i = 0; i < 4; ++i)
#pragma unroll
        for (int j = 0; j < 4; ++j)
#pragma unroll
            for (int rr = 0; rr < 4; ++rr) {
                const int gm = m0 + wm * 64 + i * 16 + quad * 4 + rr;
                const int gn = n0 + wn * 64 + j * 16 + l16;
                float v = acc[i][j][rr] + bias[gn];
                if (relu) v = fmaxf(v, 0.f);
                if (resid) v += resid[(size_t)gm * N + gn];
                if (outF) outF[(size_t)gm * N + gn] = v;
                if (outB) outB[(size_t)gm * N + gn] = f2bf(v);
            }
}

// ---------------- V^T extraction: qkv V-cols -> vtg[bh][64][4096] -------------------
__global__ __launch_bounds__(256) void vt_extract(
    const unsigned short* __restrict__ qkv, unsigned short* __restrict__ vtg)
{
    __shared__ unsigned short tile[64][72];
    const int bh = blockIdx.x, b = bh / HH, h = bh % HH;
    const int s0 = blockIdx.y * 64;
    const int tid = threadIdx.x;
#pragma unroll
    for (int p = 0; p < 2; ++p) {
        int idx = tid + p * 256;
        int r = idx >> 3, ch8 = (idx & 7) * 8;
        *(uint4*)&tile[r][ch8] =
            *(const uint4*)&qkv[(size_t)(b * SEQ + s0 + r) * 2304 + 1536 + h * 64 + ch8];
    }
    __syncthreads();
#pragma unroll
    for (int p = 0; p < 2; ++p) {
        int idx = tid + p * 256;
        int d = idx >> 3, sc = (idx & 7) * 8;
        unsigned short tmp[8];
#pragma unroll
        for (int j = 0; j < 8; ++j) tmp[j] = tile[sc + j][d];
        *(uint4*)&vtg[((size_t)bh * 64 + d) * SEQ + s0 + sc] = *(uint4*)tmp;
    }
}

// ---------------- flash attention v5: unsafe-softmax fast path, exp2 domain ---------
// Q carries 0.125*log2(e); scores are in log2 domain. mask==1 path: p=exp2(s) with
// NO running max / NO per-iter reductions (deferred row-sum). Mask path: safe online.
__global__ __launch_bounds__(256, 2) void flash_attn5(
    const unsigned short* __restrict__ qkv, const unsigned short* __restrict__ vtg,
    const float* __restrict__ mask, const int* __restrict__ maskflag,
    float* __restrict__ ctx)
{
    __shared__ __align__(16) unsigned short Ks[128][72];       // stride 36 dw == 4 mod 32
    __shared__ __align__(16) unsigned short Vt[64][136];       // stride 68 dw == 4 mod 32
    __shared__ __align__(16) unsigned short Ps[4][2][16][136];
    const int tid = threadIdx.x;
    const int lane = tid & 63, wave = tid >> 6;
    const int quad = lane >> 4, l16 = lane & 15;
    const int bh = blockIdx.y, b = bh / HH, h = bh % HH;
    const int qbase = blockIdx.x * 128 + wave * 32;
    const int use_mask = *maskflag;

    bf16x8 qf[2][2];
#pragma unroll
    for (int mt = 0; mt < 2; ++mt) {
        const size_t qrow = (size_t)(b * SEQ + qbase + mt * 16 + l16) * 2304 + h * 64;
        qf[mt][0] = ld_bf8(&qkv[qrow + quad * 8]);
        qf[mt][1] = ld_bf8(&qkv[qrow + 32 + quad * 8]);
    }
    const f32x4 fzero = {0.f, 0.f, 0.f, 0.f};
    float l_run[2][4];
    f32x4 o[2][4];
#pragma unroll
    for (int mt = 0; mt < 2; ++mt)
#pragma unroll
        for (int r = 0; r < 4; ++r) { l_run[mt][r] = 0.f; o[mt][r] = fzero; }

    const float* mbase = mask + (size_t)b * SEQ * SEQ;
    const unsigned short* kgbase = qkv + (size_t)b * SEQ * 2304 + 768 + h * 64;
    const unsigned short* vgbase = vtg + (size_t)bh * 64 * SEQ;

    if (!use_mask) {
        // ======================= FAST PATH (mask == all-ones) =======================
        float lsum[2][4];
#pragma unroll
        for (int mt = 0; mt < 2; ++mt)
#pragma unroll
            for (int r = 0; r < 4; ++r) lsum[mt][r] = 0.f;

        for (int k0 = 0; k0 < SEQ; k0 += 128) {
            __syncthreads();
#pragma unroll
            for (int p = 0; p < 4; ++p) {
                int idx = tid + p * 256;
                int row = idx >> 3, ch8 = (idx & 7) * 8;
                *(uint4*)&Ks[row][ch8] = *(const uint4*)&kgbase[(size_t)(k0 + row) * 2304 + ch8];
            }
#pragma unroll
            for (int p = 0; p < 4; ++p) {
                int idx = tid + p * 256;
                int d = idx >> 4, ch8 = (idx & 15) * 8;
                *(uint4*)&Vt[d][ch8] = *(const uint4*)&vgbase[(size_t)d * SEQ + k0 + ch8];
            }
            __syncthreads();

            f32x4 st[2][8];
#pragma unroll
            for (int j = 0; j < 8; ++j) {
                bf16x8 kf0 = ld_bf8(&Ks[j * 16 + l16][quad * 8]);
                bf16x8 kf1 = ld_bf8(&Ks[j * 16 + l16][32 + quad * 8]);
                st[0][j] = __builtin_amdgcn_mfma_f32_16x16x32_bf16(qf[0][0], kf0, fzero, 0, 0, 0);
                st[0][j] = __builtin_amdgcn_mfma_f32_16x16x32_bf16(qf[0][1], kf1, st[0][j], 0, 0, 0);
                st[1][j] = __builtin_amdgcn_mfma_f32_16x16x32_bf16(qf[1][0], kf0, fzero, 0, 0, 0);
                st[1][j] = __builtin_amdgcn_mfma_f32_16x16x32_bf16(qf[1][1], kf1, st[1][j], 0, 0, 0);
            }
            // p = exp2(s); defer row reduction: accumulate per-lane partial sums
#pragma unroll
            for (int mt = 0; mt < 2; ++mt) {
#pragma unroll
                for (int r = 0; r < 4; ++r) {
                    float acc = 0.f;
#pragma unroll
                    for (int j = 0; j < 8; ++j) {
                        float p = fast_exp2(st[mt][j][r]);
                        st[mt][j][r] = p;
                        acc += p;
                    }
                    lsum[mt][r] += acc;
                }
#pragma unroll
                for (int j = 0; j < 8; ++j)
#pragma unroll
                    for (int r = 0; r < 4; ++r)
                        Ps[wave][mt][quad * 4 + r][j * 16 + l16] = f2bf_trunc(st[mt][j][r]);
            }
#pragma unroll
            for (int kk = 0; kk < 4; ++kk) {
                bf16x8 pf0 = ld_bf8(&Ps[wave][0][l16][kk * 32 + quad * 8]);
                bf16x8 pf1 = ld_bf8(&Ps[wave][1][l16][kk * 32 + quad * 8]);
#pragma unroll
                for (int t = 0; t < 4; ++t) {
                    bf16x8 vf = ld_bf8(&Vt[t * 16 + l16][kk * 32 + quad * 8]);
                    o[0][t] = __builtin_amdgcn_mfma_f32_16x16x32_bf16(pf0, vf, o[0][t], 0, 0, 0);
                    o[1][t] = __builtin_amdgcn_mfma_f32_16x16x32_bf16(pf1, vf, o[1][t], 0, 0, 0);
                }
            }
        }
#pragma unroll
        for (int mt = 0; mt < 2; ++mt)
#pragma unroll
            for (int r = 0; r < 4; ++r) l_run[mt][r] = rowsum16(lsum[mt][r]);
    } else {
        // ======================= GENERAL PATH (arbitrary mult. mask) ================
        float m_run[2][4];
#pragma unroll
        for (int mt = 0; mt < 2; ++mt)
#pragma unroll
            for (int r = 0; r < 4; ++r) m_run[mt][r] = -1e30f;

        for (int k0 = 0; k0 < SEQ; k0 += 128) {
            __syncthreads();
#pragma unroll
            for (int p = 0; p < 4; ++p) {
                int idx = tid + p * 256;
                int row = idx >> 3, ch8 = (idx & 7) * 8;
                *(uint4*)&Ks[row][ch8] = *(const uint4*)&kgbase[(size_t)(k0 + row) * 2304 + ch8];
            }
#pragma unroll
            for (int p = 0; p < 4; ++p) {
                int idx = tid + p * 256;
                int d = idx >> 4, ch8 = (idx & 15) * 8;
                *(uint4*)&Vt[d][ch8] = *(const uint4*)&vgbase[(size_t)d * SEQ + k0 + ch8];
            }
            __syncthreads();

            f32x4 st[2][8];
#pragma unroll
            for (int j = 0; j < 8; ++j) {
                bf16x8 kf0 = ld_bf8(&Ks[j * 16 + l16][quad * 8]);
                bf16x8 kf1 = ld_bf8(&Ks[j * 16 + l16][32 + quad * 8]);
                st[0][j] = __builtin_amdgcn_mfma_f32_16x16x32_bf16(qf[0][0], kf0, fzero, 0, 0, 0);
                st[0][j] = __builtin_amdgcn_mfma_f32_16x16x32_bf16(qf[0][1], kf1, st[0][j], 0, 0, 0);
                st[1][j] = __builtin_amdgcn_mfma_f32_16x16x32_bf16(qf[1][0], kf0, fzero, 0, 0, 0);
                st[1][j] = __builtin_amdgcn_mfma_f32_16x16x32_bf16(qf[1][1], kf1, st[1][j], 0, 0, 0);
            }
#pragma unroll
            for (int mt = 0; mt < 2; ++mt) {
                const int qr = qbase + mt * 16 + quad * 4;
#pragma unroll
                for (int r = 0; r < 4; ++r) {
                    const float* mrow = &mbase[(size_t)(qr + r) * SEQ + k0 + l16];
#pragma unroll
                    for (int j = 0; j < 8; ++j)
                        st[mt][j][r] *= mrow[j * 16];
                }
            }
#pragma unroll
            for (int mt = 0; mt < 2; ++mt) {
                float alpha[4];
#pragma unroll
                for (int r = 0; r < 4; ++r) {
                    float mx = st[mt][0][r];
#pragma unroll
                    for (int j = 1; j < 8; ++j) mx = fmaxf(mx, st[mt][j][r]);
                    mx = rowmax16(mx);
                    const float mnew = fmaxf(m_run[mt][r], mx);
                    alpha[r] = fast_exp2(m_run[mt][r] - mnew);
                    float ssum = 0.f;
#pragma unroll
                    for (int j = 0; j < 8; ++j) {
                        st[mt][j][r] = fast_exp2(st[mt][j][r] - mnew);
                        ssum += st[mt][j][r];
                    }
                    ssum = rowsum16(ssum);
                    l_run[mt][r] = l_run[mt][r] * alpha[r] + ssum;
                    m_run[mt][r] = mnew;
                }
#pragma unroll
                for (int t = 0; t < 4; ++t)
#pragma unroll
                    for (int r = 0; r < 4; ++r) o[mt][t][r] *= alpha[r];
#pragma unroll
                for (int j = 0; j < 8; ++j)
#pragma unroll
                    for (int r = 0; r < 4; ++r)
                        Ps[wave][mt][quad * 4 + r][j * 16 + l16] = f2bf_trunc(st[mt][j][r]);
            }
#pragma unroll
            for (int kk = 0; kk < 4; ++kk) {
                bf16x8 pf0 = ld_bf8(&Ps[wave][0][l16][kk * 32 + quad * 8]);
                bf16x8 pf1 = ld_bf8(&Ps[wave][1][l16][kk * 32 + quad * 8]);
#pragma unroll
                for (int t = 0; t < 4; ++t) {
                    bf16x8 vf = ld_bf8(&Vt[t * 16 + l16][kk * 32 + quad * 8]);
                    o[0][t] = __builtin_amdgcn_mfma_f32_16x16x32_bf16(pf0, vf, o[0][t], 0, 0, 0);
                    o[1][t] = __builtin_amdgcn_mfma_f32_16x16x32_bf16(pf1, vf, o[1][t], 0, 0, 0);
                }
            }
        }
    }

#pragma unroll
    for (int mt = 0; mt < 2; ++mt)
#pragma unroll
        for (int t = 0; t < 4; ++t)
#pragma unroll
            for (int r = 0; r < 4; ++r) {
                const int row = qbase + mt * 16 + quad * 4 + r;
                ctx[(size_t)(b * SEQ + row) * DD + h * 64 + t * 16 + l16] =
                    o[mt][t][r] / l_run[mt][r];
            }
}

// -----------------------------------------------------------------------------------
extern "C" void kernel_launch(void* const* d_in, const int* in_sizes, int n_in,
                              void* d_out, int out_size, void* d_ws, size_t ws_size,
                              hipStream_t stream)
{
    (void)in_sizes; (void)n_in; (void)out_size; (void)ws_size;
    const float* x      = (const float*)d_in[0];
    const float* mask   = (const float*)d_in[1];
    const float* wq     = (const float*)d_in[2];
    const float* bq     = (const float*)d_in[3];
    const float* wk     = (const float*)d_in[4];
    const float* bk     = (const float*)d_in[5];
    const float* wv     = (const float*)d_in[6];
    const float* bv     = (const float*)d_in[7];
    // d_in[8]=wo, d_in[9]=bo: reference never applies out_linear — intentionally unused
    const float* w1     = (const float*)d_in[10];
    const float* b1     = (const float*)d_in[11];
    const float* w2     = (const float*)d_in[12];
    const float* b2     = (const float*)d_in[13];
    const float* gamma1 = (const float*)d_in[14];
    const float* beta1  = (const float*)d_in[15];
    const float* gamma2 = (const float*)d_in[16];
    const float* beta2  = (const float*)d_in[17];
    float* out = (float*)d_out;

    char* ws = (char*)d_ws;
    size_t off = 0;
    auto take = [&](size_t bytes) -> char* {
        char* p = ws + off;
        off = (off + bytes + 255) & ~(size_t)255;
        return p;
    };
    unsigned short* wqkvT = (unsigned short*)take((size_t)2304 * 768 * 2);
    unsigned short* w1T   = (unsigned short*)take((size_t)3072 * 768 * 2);
    unsigned short* w2T   = (unsigned short*)take((size_t)768 * 3072 * 2);
    float*          bqkv  = (float*)take(2304 * 4);
    int*            mflag = (int*)take(256);
    unsigned short* l12   = (unsigned short*)take((size_t)NTOK * DD * 2);
    unsigned short* qkv   = (unsigned short*)take((size_t)NTOK * 2304 * 2);
    float*          x1    = (float*)take((size_t)NTOK * DD * 4);
    // big region (50.3 MB): during attention = [ctx 25.2 MB | vtg 25.2 MB]; later hb.
    char*           big   = take((size_t)NTOK * DFFN * 2);
    float*          ctx   = (float*)big;
    unsigned short* vtg   = (unsigned short*)(big + (size_t)NTOK * DD * 4);
    unsigned short* hb    = (unsigned short*)big;

    (void)hipMemsetAsync(mflag, 0, 4, stream);
    mask_check<<<2048, 256, 0, stream>>>(mask, mflag);

    // weight prep (QK_SCALE = 0.125*log2e folded into wq/bq -> scores in log2 domain)
    transpose_f32_to_bf16<<<dim3(24, 24), dim3(32, 8), 0, stream>>>(wq, wqkvT,                 768, 768, QK_SCALE);
    transpose_f32_to_bf16<<<dim3(24, 24), dim3(32, 8), 0, stream>>>(wk, wqkvT + 768 * 768,     768, 768, 1.0f);
    transpose_f32_to_bf16<<<dim3(24, 24), dim3(32, 8), 0, stream>>>(wv, wqkvT + 2 * 768 * 768, 768, 768, 1.0f);
    transpose_f32_to_bf16<<<dim3(96, 24), dim3(32, 8), 0, stream>>>(w1, w1T,                   768, 3072, 1.0f);
    transpose_f32_to_bf16<<<dim3(24, 96), dim3(32, 8), 0, stream>>>(w2, w2T,                   3072, 768, 1.0f);
    concat_bias<<<9, 256, 0, stream>>>(bq, bk, bv, bqkv);

    // LN1 -> l1 (bf16)
    ln_fused<<<NTOK, 256, 0, stream>>>(x, nullptr, gamma1, beta1, l12, nullptr);
    // fused QKV GEMM
    gemm_bf16<<<dim3(2304 / 128, NTOK / 128), 256, 0, stream>>>(
        l12, wqkvT, bqkv, nullptr, qkv, nullptr, NTOK, 2304, 768, 0);
    // V^T per head
    vt_extract<<<dim3(BB * HH, SEQ / 64), 256, 0, stream>>>(qkv, vtg);
    // flash attention v5 -> ctx fp32
    flash_attn5<<<dim3(SEQ / 128, BB * HH), 256, 0, stream>>>(qkv, vtg, mask, mflag, ctx);
    // x1 = x + ctx, LN2 -> l2 (bf16)
    ln_fused<<<NTOK, 256, 0, stream>>>(x, ctx, gamma2, beta2, l12, x1);
    // FFN1: relu(l2 @ w1 + b1) -> hb
    gemm_bf16<<<dim3(3072 / 128, NTOK / 128), 256, 0, stream>>>(
        l12, w1T, b1, nullptr, hb, nullptr, NTOK, 3072, 768, 1);
    // FFN2: hb @ w2 + b2 + x1 -> out
    gemm_bf16<<<dim3(768 / 128, NTOK / 128), 256, 0, stream>>>(
        hb, w2T, b2, x1, nullptr, out, NTOK, 768, 3072, 0);
}